// Round 1
// baseline (1705.819 us; speedup 1.0000x reference)
//
#include <hip/hip_runtime.h>
#include <math.h>
#include <stdint.h>

#define B_   4
#define H_   8
#define BH   32
#define T_   8192
#define D_   64
#define NC_  128
#define WSZ_ 64
#define CAND_CAP 512

typedef unsigned short u16;
typedef short frag8 __attribute__((ext_vector_type(8)));
typedef float floatx4 __attribute__((ext_vector_type(4)));

__device__ inline u16 f2bf(float f) {
    unsigned int u = __float_as_uint(f);
    unsigned int r = (u + 0x7fffu + ((u >> 16) & 1u)) >> 16;
    return (u16)r;
}

// ---------------- Kernel A: bf16 MFMA dists + aux loss ----------------
// block: 256 thr, 64 tokens x 128 clusters. grid: (256 tiles over 2T, CH pairs)
__global__ __launch_bounds__(256) void dist_kernel(
    const float* __restrict__ qg, const float* __restrict__ kg,
    const float* __restrict__ means, u16* __restrict__ dbuf,
    double* __restrict__ aux_sum, int pair0)
{
    __shared__ float s_x[64 * 64];       // normalized fp32 tokens
    __shared__ u16   s_xb[64 * 80];      // bf16, padded stride 80 (bank spread)
    __shared__ u16   s_mb[128 * 80];     // bf16 means, padded
    __shared__ int   s_argc[64];
    __shared__ float s_aux;
    const int tid = threadIdx.x;
    const int bh = pair0 + blockIdx.y;
    const int h  = bh & 7;
    const int tok0 = blockIdx.x * 64;            // within [0, 2T)
    const int isK  = (tok0 >= T_) ? 1 : 0;
    const int tloc0 = isK ? tok0 - T_ : tok0;
    const float* src = isK ? kg : qg;

    if (tid == 0) s_aux = 0.f;
    const float* mh = means + (size_t)h * NC_ * D_;
    for (int i = tid; i < NC_ * D_; i += 256)
        s_mb[(i >> 6) * 80 + (i & 63)] = f2bf(mh[i]);
    const float* sp = src + ((size_t)bh * T_ + tloc0) * D_;
    for (int i = tid; i < 64 * D_; i += 256) s_x[i] = sp[i];
    __syncthreads();
    // normalize: 4 threads per token row
    {
        const int row = tid >> 2, sub = tid & 3;
        float ss = 0.f;
        #pragma unroll
        for (int e = 0; e < 16; e++) { float vv = s_x[row*64 + sub*16 + e]; ss += vv*vv; }
        ss += __shfl_xor(ss, 1); ss += __shfl_xor(ss, 2);
        const float rn = 1.0f / fmaxf(sqrtf(ss), 1e-12f);
        #pragma unroll
        for (int e = 0; e < 16; e++) {
            float vv = s_x[row*64 + sub*16 + e] * rn;
            s_x[row*64 + sub*16 + e] = vv;
            s_xb[row*80 + sub*16 + e] = f2bf(vv);
        }
    }
    __syncthreads();
    // MFMA: wave w covers tokens [w*16, w*16+16), all 128 clusters
    {
        const int w = tid >> 6, lane = tid & 63;
        const int mrow = lane & 15, quad = lane >> 4;
        const frag8 a0 = *(const frag8*)&s_xb[(w*16 + mrow)*80 + quad*8];
        const frag8 a1 = *(const frag8*)&s_xb[(w*16 + mrow)*80 + 32 + quad*8];
        float bv[4]; int bc[4];
        #pragma unroll
        for (int r = 0; r < 4; r++) { bv[r] = -1e30f; bc[r] = 0; }
        const int tokw = w * 16 + quad * 4;      // token base of my C rows
        for (int n = 0; n < 8; n++) {
            const frag8 b0 = *(const frag8*)&s_mb[(n*16 + mrow)*80 + quad*8];
            const frag8 b1 = *(const frag8*)&s_mb[(n*16 + mrow)*80 + 32 + quad*8];
            floatx4 acc = {0.f, 0.f, 0.f, 0.f};
            acc = __builtin_amdgcn_mfma_f32_16x16x32_bf16(a0, b0, acc, 0, 0, 0);
            acc = __builtin_amdgcn_mfma_f32_16x16x32_bf16(a1, b1, acc, 0, 0, 0);
            const int cc = n*16 + mrow;          // cluster (C col = lane&15)
            u16 o0 = f2bf(acc[0]), o1 = f2bf(acc[1]), o2 = f2bf(acc[2]), o3 = f2bf(acc[3]);
            uint2 pk; pk.x = (unsigned)o0 | ((unsigned)o1 << 16);
                      pk.y = (unsigned)o2 | ((unsigned)o3 << 16);
            *(uint2*)&dbuf[(((size_t)blockIdx.y*2 + isK)*NC_ + cc)*T_ + tloc0 + tokw] = pk;
            #pragma unroll
            for (int r = 0; r < 4; r++)
                if (acc[r] > bv[r]) { bv[r] = acc[r]; bc[r] = cc; } // n asc => lowest c on ties
        }
        #pragma unroll
        for (int m = 1; m < 16; m <<= 1) {
            #pragma unroll
            for (int r = 0; r < 4; r++) {
                float ov = __shfl_xor(bv[r], m);
                int   oc = __shfl_xor(bc[r], m);
                if (ov > bv[r] || (ov == bv[r] && oc < bc[r])) { bv[r] = ov; bc[r] = oc; }
            }
        }
        if (mrow == 0) {
            #pragma unroll
            for (int r = 0; r < 4; r++) s_argc[tokw + r] = bc[r];
        }
    }
    __syncthreads();
    // aux residual: 4 threads per token; fp32 x_hat vs fp32 global means
    {
        const int row = tid >> 2, sub = tid & 3;
        const int c = s_argc[row];
        const float* mr = means + ((size_t)h*NC_ + c)*D_ + sub*16;
        float rs = 0.f;
        #pragma unroll
        for (int e = 0; e < 16; e++) {
            float dd = s_x[row*64 + sub*16 + e] - mr[e];
            rs += dd*dd;
        }
        rs += __shfl_xor(rs, 1); rs += __shfl_xor(rs, 2);
        if (sub == 0) atomicAdd(&s_aux, rs);
    }
    __syncthreads();
    if (tid == 0) atomicAdd(aux_sum, (double)s_aux);
}

// ---------------- Kernel B: margined candidate select + fp64 exact top-64 ----------------
__global__ __launch_bounds__(256) void topk_kernel(
    const u16* __restrict__ dbuf, const float* __restrict__ qg,
    const float* __restrict__ kg, const float* __restrict__ means,
    int* __restrict__ idx_q, int* __restrict__ idx_k, int pair0)
{
    __shared__ int s_hist[4096];
    __shared__ int s_scan[256];
    __shared__ int s_B, s_cnt;
    __shared__ int s_cand[CAND_CAP];
    __shared__ unsigned long long s_key[CAND_CAP];
    __shared__ int s_sidx[CAND_CAP];
    __shared__ double s_mean[64];

    const int tid = threadIdx.x;
    const int c = blockIdx.x, isK = blockIdx.y, pl = blockIdx.z;
    const int bh = pair0 + pl, h = bh & 7;
    const u16* row = dbuf + (((size_t)pl*2 + isK)*NC_ + c)*T_;

    for (int i = tid; i < 4096; i += 256) s_hist[i] = 0;
    __syncthreads();
    u16 vals[32];
    #pragma unroll
    for (int j = 0; j < 32; j++) {
        u16 u = row[tid + j*256];
        vals[j] = u;
        unsigned int s = (u & 0x8000u) ? (unsigned int)((~u) & 0xffffu) : (unsigned int)(u | 0x8000u);
        atomicAdd(&s_hist[s >> 4], 1);
    }
    __syncthreads();
    int cs = 0;
    #pragma unroll
    for (int b2 = 0; b2 < 16; b2++) cs += s_hist[tid*16 + b2];
    s_scan[tid] = cs;
    __syncthreads();
    for (int off = 1; off < 256; off <<= 1) {
        int add = (tid + off < 256) ? s_scan[tid + off] : 0;
        __syncthreads();
        s_scan[tid] += add;
        __syncthreads();
    }
    {
        int Tj = s_scan[tid];
        int Tn = (tid < 255) ? s_scan[tid + 1] : 0;
        if (Tj >= WSZ_ && Tn < WSZ_) {          // rank-64 bin lives in my 16-bin chunk
            int running = Tn, Bb = tid * 16;
            for (int b2 = tid*16 + 15; b2 >= tid*16; b2--) {
                running += s_hist[b2];
                if (running >= WSZ_) { Bb = b2; break; }
            }
            s_B = Bb;
        }
    }
    __syncthreads();
    int thr = s_B - 2; if (thr < 0) thr = 0;    // 2-bin margin >= 0.25 abs >> 2*eps(bf16)
    for (;;) {
        if (tid == 0) s_cnt = 0;
        __syncthreads();
        #pragma unroll
        for (int j = 0; j < 32; j++) {
            u16 u = vals[j];
            unsigned int s = (u & 0x8000u) ? (unsigned int)((~u) & 0xffffu) : (unsigned int)(u | 0x8000u);
            if ((int)(s >> 4) >= thr) {
                int p = atomicAdd(&s_cnt, 1);
                if (p < CAND_CAP) s_cand[p] = tid + j*256;
            }
        }
        __syncthreads();
        if (s_cnt <= CAND_CAP) break;
        thr++;
        __syncthreads();
    }
    const int M = s_cnt;  // >= 64 guaranteed by construction
    if (tid < 64) s_mean[tid] = (double)means[((size_t)h*NC_ + c)*D_ + tid];
    __syncthreads();
    const float* src = isK ? kg : qg;
    for (int p = tid; p < CAND_CAP; p += 256) {
        if (p < M) {
            const int tok = s_cand[p];
            const float* xr = src + ((size_t)bh*T_ + tok)*D_;
            double dot = 0.0, ss = 0.0;
            #pragma unroll
            for (int d = 0; d < 64; d++) {
                double xv = (double)xr[d];
                dot += xv * s_mean[d];
                ss  += xv * xv;
            }
            double val = dot / fmax(sqrt(ss), 1e-12);
            unsigned long long u = (unsigned long long)__double_as_longlong(val);
            u = (u & 0x8000000000000000ull) ? ~u : (u | 0x8000000000000000ull);
            s_key[p] = u;
            s_sidx[p] = tok;
        } else {
            s_key[p] = 0ull;           // below any real (non-NaN) key
            s_sidx[p] = 0x7fffffff;
        }
    }
    __syncthreads();
    // bitonic sort, best-first: (key desc, idx asc)
    for (int ksz = 2; ksz <= CAND_CAP; ksz <<= 1) {
        for (int j = ksz >> 1; j > 0; j >>= 1) {
            #pragma unroll
            for (int rep = 0; rep < 2; rep++) {
                int i = tid + rep*256;
                int ixj = i ^ j;
                if (ixj > i) {
                    unsigned long long ka = s_key[i], kb = s_key[ixj];
                    int ia = s_sidx[i], ib = s_sidx[ixj];
                    bool less_ab = (ka > kb) || (ka == kb && ia < ib);
                    bool less_ba = (kb > ka) || (kb == ka && ib < ia);
                    bool up = ((i & ksz) == 0);
                    if (up ? less_ba : less_ab) {
                        s_key[i] = kb; s_key[ixj] = ka;
                        s_sidx[i] = ib; s_sidx[ixj] = ia;
                    }
                }
            }
            __syncthreads();
        }
    }
    if (tid < WSZ_) {
        int* dst = (isK ? idx_k : idx_q) + ((size_t)bh*NC_ + c)*WSZ_;
        dst[tid] = s_sidx[tid];
    }
}

// ---------------- Kernel C: selection counts (scatter denominator) ----------------
__global__ __launch_bounds__(256) void count_kernel(
    const int* __restrict__ idx_q, int* __restrict__ counts)
{
    int i = blockIdx.x * 256 + threadIdx.x;   // 0 .. BH*NC*WSZ-1
    int bh = i >> 13;                         // 128*64 = 8192 entries per bh
    atomicAdd(&counts[bh * T_ + idx_q[i]], 1);
}

// ---------------- Kernel D: per-cluster attention + atomic scatter ----------------
__global__ __launch_bounds__(256) void attn_kernel(
    const float* __restrict__ qg, const float* __restrict__ kg, const float* __restrict__ vg,
    const float* __restrict__ mem_k, const float* __restrict__ mem_v,
    const int* __restrict__ idx_q, const int* __restrict__ idx_k,
    float* __restrict__ out)
{
    __shared__ float s_k[65 * D_];
    __shared__ float s_v[65 * D_];
    __shared__ int s_qi[WSZ_], s_ki[WSZ_];
    const int tid = threadIdx.x;
    const int c = blockIdx.x, bh = blockIdx.y, h = bh & 7;
    const int* qi = idx_q + ((size_t)bh*NC_ + c)*WSZ_;
    const int* ki = idx_k + ((size_t)bh*NC_ + c)*WSZ_;
    if (tid < WSZ_) { s_qi[tid] = qi[tid]; s_ki[tid] = ki[tid]; }
    __syncthreads();
    for (int i = tid; i < 65 * D_; i += 256) {
        int r = i >> 6, d = i & 63;
        float kv, vv;
        if (r == 0) {
            kv = mem_k[((size_t)h*NC_ + c)*D_ + d];
            vv = mem_v[((size_t)h*NC_ + c)*D_ + d];
        } else {
            int tok = s_ki[r-1];
            kv = kg[((size_t)bh*T_ + tok)*D_ + d];
            vv = vg[((size_t)bh*T_ + tok)*D_ + d];
        }
        s_k[i] = kv; s_v[i] = vv;
    }
    __syncthreads();
    const int rowi = tid >> 2, quad = tid & 3;   // 64 q-rows x 4 lanes
    const int tok = s_qi[rowi];
    const float* qr = qg + ((size_t)bh*T_ + tok)*D_ + quad*16;
    float qreg[16];
    #pragma unroll
    for (int i = 0; i < 16; i++) qreg[i] = qr[i];
    float m = -1e30f, l = 0.f, acc[16];
    #pragma unroll
    for (int i = 0; i < 16; i++) acc[i] = 0.f;
    for (int j = 0; j < 65; j++) {
        const float* krow = s_k + j*D_ + quad*16;
        float p = 0.f;
        #pragma unroll
        for (int i = 0; i < 16; i++) p += qreg[i] * krow[i];
        p += __shfl_xor(p, 1);
        p += __shfl_xor(p, 2);
        float s = p * 0.125f;                 // d^-0.5
        float nm = fmaxf(m, s);
        float eo = __expf(m - nm);
        float en = __expf(s - nm);
        l = l * eo + en;
        const float* vrow = s_v + j*D_ + quad*16;
        #pragma unroll
        for (int i = 0; i < 16; i++) acc[i] = acc[i]*eo + en*vrow[i];
        m = nm;
    }
    float rl = 1.f / l;
    float* orow = out + ((size_t)bh*T_ + tok)*D_ + quad*16;
    #pragma unroll
    for (int i = 0; i < 16; i++) atomicAdd(&orow[i], acc[i] * rl);
}

// ---------------- Kernel E: finalize (divide by count+eps, write aux) ----------------
__global__ __launch_bounds__(256) void fin_kernel(
    float* __restrict__ out, const int* __restrict__ counts,
    const double* __restrict__ aux_sum)
{
    size_t i = (size_t)blockIdx.x * 256 + threadIdx.x;   // float4 index, 4194304 total
    float4* o4 = (float4*)out;
    float4 vx = o4[i];
    int cnt = counts[i >> 4];
    float r = 1.f / ((float)cnt + 1e-5f);
    vx.x *= r; vx.y *= r; vx.z *= r; vx.w *= r;
    o4[i] = vx;
    if (blockIdx.x == 0 && threadIdx.x == 0)
        out[(size_t)BH * T_ * D_] = (float)(aux_sum[0] * (0.0001 / 33554432.0));
}

extern "C" void kernel_launch(void* const* d_in, const int* in_sizes, int n_in,
                              void* d_out, int out_size, void* d_ws, size_t ws_size,
                              hipStream_t stream)
{
    const float* q      = (const float*)d_in[0];
    const float* k      = (const float*)d_in[1];
    const float* v      = (const float*)d_in[2];
    const float* means  = (const float*)d_in[3];
    const float* mem_k  = (const float*)d_in[4];
    const float* mem_v  = (const float*)d_in[5];
    float* out = (float*)d_out;

    char* ws = (char*)d_ws;
    const size_t o_counts = 256;                                   // [0,256): aux double
    const size_t o_idxq = o_counts + (size_t)BH * T_ * sizeof(int);
    const size_t o_idxk = o_idxq + (size_t)BH * NC_ * WSZ_ * sizeof(int);
    size_t o_dbuf = o_idxk + (size_t)BH * NC_ * WSZ_ * sizeof(int);
    o_dbuf = (o_dbuf + 255) & ~(size_t)255;

    double* aux  = (double*)ws;
    int* counts  = (int*)(ws + o_counts);
    int* idxq    = (int*)(ws + o_idxq);
    int* idxk    = (int*)(ws + o_idxk);
    u16* dbuf    = (u16*)(ws + o_dbuf);

    const size_t per_pair = (size_t)2 * NC_ * T_ * sizeof(u16);    // 4 MiB
    int CH = 32;
    while (CH > 1 && o_dbuf + (size_t)CH * per_pair > ws_size) CH >>= 1;

    hipMemsetAsync(d_out, 0, (size_t)out_size * sizeof(float), stream);
    hipMemsetAsync(d_ws, 0, o_idxq, stream);   // zero aux + counts

    for (int p0 = 0; p0 < BH; p0 += CH) {
        dim3 gA(256, CH);
        dist_kernel<<<gA, 256, 0, stream>>>(q, k, means, dbuf, aux, p0);
        dim3 gB(NC_, 2, CH);
        topk_kernel<<<gB, 256, 0, stream>>>(dbuf, q, k, means, idxq, idxk, p0);
    }
    count_kernel<<<dim3(BH * NC_ * WSZ_ / 256), 256, 0, stream>>>(idxq, counts);
    attn_kernel<<<dim3(NC_, BH), 256, 0, stream>>>(q, k, v, mem_k, mem_v, idxq, idxk, out);
    fin_kernel<<<dim3((unsigned)((size_t)BH * T_ * D_ / 4 / 256)), 256, 0, stream>>>(out, counts, aux);
}

// Round 2
// 923.853 us; speedup vs baseline: 1.8464x; 1.8464x over previous
//
#include <hip/hip_runtime.h>
#include <math.h>
#include <stdint.h>

#define B_   4
#define H_   8
#define BH   32
#define T_   8192
#define D_   64
#define NC_  128
#define WSZ_ 64
#define CAND_CAP 512

typedef unsigned short u16;
typedef short frag8 __attribute__((ext_vector_type(8)));
typedef float floatx4 __attribute__((ext_vector_type(4)));

__device__ inline u16 f2bf(float f) {
    unsigned int u = __float_as_uint(f);
    unsigned int r = (u + 0x7fffu + ((u >> 16) & 1u)) >> 16;
    return (u16)r;
}

// ---------------- Kernel A: bf16 MFMA dists + aux loss ----------------
__global__ __launch_bounds__(256) void dist_kernel(
    const float* __restrict__ qg, const float* __restrict__ kg,
    const float* __restrict__ means, u16* __restrict__ dbuf,
    double* __restrict__ aux_sum, int pair0)
{
    __shared__ float s_x[64 * 64];       // normalized fp32 tokens
    __shared__ u16   s_xb[64 * 80];      // bf16, padded stride 80
    __shared__ u16   s_mb[128 * 80];     // bf16 means, padded
    __shared__ int   s_argc[64];
    __shared__ float s_aux;
    const int tid = threadIdx.x;
    const int bh = pair0 + blockIdx.y;
    const int h  = bh & 7;
    const int tok0 = blockIdx.x * 64;            // within [0, 2T)
    const int isK  = (tok0 >= T_) ? 1 : 0;
    const int tloc0 = isK ? tok0 - T_ : tok0;
    const float* src = isK ? kg : qg;

    if (tid == 0) s_aux = 0.f;
    const float* mh = means + (size_t)h * NC_ * D_;
    for (int i = tid; i < NC_ * D_; i += 256)
        s_mb[(i >> 6) * 80 + (i & 63)] = f2bf(mh[i]);
    const float* sp = src + ((size_t)bh * T_ + tloc0) * D_;
    for (int i = tid; i < 64 * D_; i += 256) s_x[i] = sp[i];
    __syncthreads();
    {
        const int row = tid >> 2, sub = tid & 3;
        float ss = 0.f;
        #pragma unroll
        for (int e = 0; e < 16; e++) { float vv = s_x[row*64 + sub*16 + e]; ss += vv*vv; }
        ss += __shfl_xor(ss, 1); ss += __shfl_xor(ss, 2);
        const float rn = 1.0f / fmaxf(sqrtf(ss), 1e-12f);
        #pragma unroll
        for (int e = 0; e < 16; e++) {
            float vv = s_x[row*64 + sub*16 + e] * rn;
            s_x[row*64 + sub*16 + e] = vv;
            s_xb[row*80 + sub*16 + e] = f2bf(vv);
        }
    }
    __syncthreads();
    {
        const int w = tid >> 6, lane = tid & 63;
        const int mrow = lane & 15, quad = lane >> 4;
        const frag8 a0 = *(const frag8*)&s_xb[(w*16 + mrow)*80 + quad*8];
        const frag8 a1 = *(const frag8*)&s_xb[(w*16 + mrow)*80 + 32 + quad*8];
        float bv[4]; int bc[4];
        #pragma unroll
        for (int r = 0; r < 4; r++) { bv[r] = -1e30f; bc[r] = 0; }
        const int tokw = w * 16 + quad * 4;
        for (int n = 0; n < 8; n++) {
            const frag8 b0 = *(const frag8*)&s_mb[(n*16 + mrow)*80 + quad*8];
            const frag8 b1 = *(const frag8*)&s_mb[(n*16 + mrow)*80 + 32 + quad*8];
            floatx4 acc = {0.f, 0.f, 0.f, 0.f};
            acc = __builtin_amdgcn_mfma_f32_16x16x32_bf16(a0, b0, acc, 0, 0, 0);
            acc = __builtin_amdgcn_mfma_f32_16x16x32_bf16(a1, b1, acc, 0, 0, 0);
            const int cc = n*16 + mrow;
            u16 o0 = f2bf(acc[0]), o1 = f2bf(acc[1]), o2 = f2bf(acc[2]), o3 = f2bf(acc[3]);
            uint2 pk; pk.x = (unsigned)o0 | ((unsigned)o1 << 16);
                      pk.y = (unsigned)o2 | ((unsigned)o3 << 16);
            *(uint2*)&dbuf[(((size_t)blockIdx.y*2 + isK)*NC_ + cc)*T_ + tloc0 + tokw] = pk;
            #pragma unroll
            for (int r = 0; r < 4; r++)
                if (acc[r] > bv[r]) { bv[r] = acc[r]; bc[r] = cc; }
        }
        #pragma unroll
        for (int m = 1; m < 16; m <<= 1) {
            #pragma unroll
            for (int r = 0; r < 4; r++) {
                float ov = __shfl_xor(bv[r], m);
                int   oc = __shfl_xor(bc[r], m);
                if (ov > bv[r] || (ov == bv[r] && oc < bc[r])) { bv[r] = ov; bc[r] = oc; }
            }
        }
        if (mrow == 0) {
            #pragma unroll
            for (int r = 0; r < 4; r++) s_argc[tokw + r] = bc[r];
        }
    }
    __syncthreads();
    {
        const int row = tid >> 2, sub = tid & 3;
        const int c = s_argc[row];
        const float* mr = means + ((size_t)h*NC_ + c)*D_ + sub*16;
        float rs = 0.f;
        #pragma unroll
        for (int e = 0; e < 16; e++) {
            float dd = s_x[row*64 + sub*16 + e] - mr[e];
            rs += dd*dd;
        }
        rs += __shfl_xor(rs, 1); rs += __shfl_xor(rs, 2);
        if (sub == 0) atomicAdd(&s_aux, rs);
    }
    __syncthreads();
    if (tid == 0) atomicAdd(aux_sum, (double)s_aux);
}

// ---------------- Kernel B: margined candidate select + fp64 exact top-64 ----------------
__global__ __launch_bounds__(256) void topk_kernel(
    const u16* __restrict__ dbuf, const float* __restrict__ qg,
    const float* __restrict__ kg, const float* __restrict__ means,
    int* __restrict__ idx_q, int* __restrict__ idx_k, int pair0)
{
    __shared__ int s_hist[4096];
    __shared__ int s_scan[256];
    __shared__ int s_B, s_cnt;
    __shared__ int s_cand[CAND_CAP];
    __shared__ unsigned long long s_key[CAND_CAP];
    __shared__ int s_sidx[CAND_CAP];
    __shared__ double s_mean[64];

    const int tid = threadIdx.x;
    const int c = blockIdx.x, isK = blockIdx.y, pl = blockIdx.z;
    const int bh = pair0 + pl, h = bh & 7;
    const u16* row = dbuf + (((size_t)pl*2 + isK)*NC_ + c)*T_;

    for (int i = tid; i < 4096; i += 256) s_hist[i] = 0;
    __syncthreads();
    u16 vals[32];
    #pragma unroll
    for (int j = 0; j < 32; j++) {
        u16 u = row[tid + j*256];
        vals[j] = u;
        unsigned int s = (u & 0x8000u) ? (unsigned int)((~u) & 0xffffu) : (unsigned int)(u | 0x8000u);
        atomicAdd(&s_hist[s >> 4], 1);
    }
    __syncthreads();
    int cs = 0;
    #pragma unroll
    for (int b2 = 0; b2 < 16; b2++) cs += s_hist[tid*16 + b2];
    s_scan[tid] = cs;
    __syncthreads();
    for (int off = 1; off < 256; off <<= 1) {
        int add = (tid + off < 256) ? s_scan[tid + off] : 0;
        __syncthreads();
        s_scan[tid] += add;
        __syncthreads();
    }
    {
        int Tj = s_scan[tid];
        int Tn = (tid < 255) ? s_scan[tid + 1] : 0;
        if (Tj >= WSZ_ && Tn < WSZ_) {
            int running = Tn, Bb = tid * 16;
            for (int b2 = tid*16 + 15; b2 >= tid*16; b2--) {
                running += s_hist[b2];
                if (running >= WSZ_) { Bb = b2; break; }
            }
            s_B = Bb;
        }
    }
    __syncthreads();
    int thr = s_B - 2; if (thr < 0) thr = 0;
    for (;;) {
        if (tid == 0) s_cnt = 0;
        __syncthreads();
        #pragma unroll
        for (int j = 0; j < 32; j++) {
            u16 u = vals[j];
            unsigned int s = (u & 0x8000u) ? (unsigned int)((~u) & 0xffffu) : (unsigned int)(u | 0x8000u);
            if ((int)(s >> 4) >= thr) {
                int p = atomicAdd(&s_cnt, 1);
                if (p < CAND_CAP) s_cand[p] = tid + j*256;
            }
        }
        __syncthreads();
        if (s_cnt <= CAND_CAP) break;
        thr++;
        __syncthreads();
    }
    const int M = s_cnt;
    if (tid < 64) s_mean[tid] = (double)means[((size_t)h*NC_ + c)*D_ + tid];
    __syncthreads();
    const float* src = isK ? kg : qg;
    for (int p = tid; p < CAND_CAP; p += 256) {
        if (p < M) {
            const int tok = s_cand[p];
            const float* xr = src + ((size_t)bh*T_ + tok)*D_;
            double dot = 0.0, ss = 0.0;
            #pragma unroll
            for (int d = 0; d < 64; d++) {
                double xv = (double)xr[d];
                dot += xv * s_mean[d];
                ss  += xv * xv;
            }
            double val = dot / fmax(sqrt(ss), 1e-12);
            unsigned long long u = (unsigned long long)__double_as_longlong(val);
            u = (u & 0x8000000000000000ull) ? ~u : (u | 0x8000000000000000ull);
            s_key[p] = u;
            s_sidx[p] = tok;
        } else {
            s_key[p] = 0ull;
            s_sidx[p] = 0x7fffffff;
        }
    }
    __syncthreads();
    for (int ksz = 2; ksz <= CAND_CAP; ksz <<= 1) {
        for (int j = ksz >> 1; j > 0; j >>= 1) {
            #pragma unroll
            for (int rep = 0; rep < 2; rep++) {
                int i = tid + rep*256;
                int ixj = i ^ j;
                if (ixj > i) {
                    unsigned long long ka = s_key[i], kb = s_key[ixj];
                    int ia = s_sidx[i], ib = s_sidx[ixj];
                    bool less_ab = (ka > kb) || (ka == kb && ia < ib);
                    bool less_ba = (kb > ka) || (kb == ka && ib < ia);
                    bool up = ((i & ksz) == 0);
                    if (up ? less_ba : less_ab) {
                        s_key[i] = kb; s_key[ixj] = ka;
                        s_sidx[i] = ib; s_sidx[ixj] = ia;
                    }
                }
            }
            __syncthreads();
        }
    }
    if (tid < WSZ_) {
        int* dst = (isK ? idx_k : idx_q) + ((size_t)bh*NC_ + c)*WSZ_;
        dst[tid] = s_sidx[tid];
    }
}

// ---------------- Kernel C1: selection counts ----------------
__global__ __launch_bounds__(256) void count_kernel(
    const int* __restrict__ idx_q, int* __restrict__ counts)
{
    int i = blockIdx.x * 256 + threadIdx.x;   // 0 .. BH*NC*WSZ-1
    int bh = i >> 13;
    atomicAdd(&counts[bh * T_ + idx_q[i]], 1);
}

// ---------------- Kernel C2: per-bh exclusive scan of counts -> offsets, cursor ----------------
__global__ __launch_bounds__(256) void scan_kernel(
    const int* __restrict__ counts, int* __restrict__ offsets, int* __restrict__ cursor)
{
    __shared__ int s_tmp[256];
    const int tid = threadIdx.x, bh = blockIdx.x;
    const int base = bh * T_;
    int c[32], s = 0;
    #pragma unroll
    for (int j = 0; j < 32; j++) { c[j] = counts[base + tid*32 + j]; s += c[j]; }
    s_tmp[tid] = s;
    __syncthreads();
    for (int off = 1; off < 256; off <<= 1) {
        int add = (tid >= off) ? s_tmp[tid - off] : 0;
        __syncthreads();
        s_tmp[tid] += add;
        __syncthreads();
    }
    int running = s_tmp[tid] - s + bh * (NC_ * WSZ_);   // exclusive prefix + bh base
    #pragma unroll
    for (int j = 0; j < 32; j++) {
        offsets[base + tid*32 + j] = running;
        cursor [base + tid*32 + j] = running;
        running += c[j];
    }
}

// ---------------- Kernel C3: fill CSR entries ----------------
__global__ __launch_bounds__(256) void fill_kernel(
    const int* __restrict__ idx_q, int* __restrict__ cursor, u16* __restrict__ entries)
{
    int i = blockIdx.x * 256 + threadIdx.x;   // 0 .. BH*NC*WSZ-1
    int bh = i >> 13;
    int tok = idx_q[i];
    int pos = atomicAdd(&cursor[bh * T_ + tok], 1);
    entries[pos] = (u16)(i & 8191);           // c*WSZ + slot
}

// ---------------- Kernel D: per-cluster attention -> dense bo (no atomics) ----------------
__global__ __launch_bounds__(256) void attn_kernel(
    const float* __restrict__ qg, const float* __restrict__ kg, const float* __restrict__ vg,
    const float* __restrict__ mem_k, const float* __restrict__ mem_v,
    const int* __restrict__ idx_q, const int* __restrict__ idx_k,
    float* __restrict__ bo)
{
    __shared__ float s_k[65 * D_];
    __shared__ float s_v[65 * D_];
    __shared__ int s_qi[WSZ_], s_ki[WSZ_];
    const int tid = threadIdx.x;
    const int c = blockIdx.x, bh = blockIdx.y, h = bh & 7;
    const int* qi = idx_q + ((size_t)bh*NC_ + c)*WSZ_;
    const int* ki = idx_k + ((size_t)bh*NC_ + c)*WSZ_;
    if (tid < WSZ_) { s_qi[tid] = qi[tid]; s_ki[tid] = ki[tid]; }
    __syncthreads();
    for (int i = tid; i < 65 * D_; i += 256) {
        int r = i >> 6, d = i & 63;
        float kv, vv;
        if (r == 0) {
            kv = mem_k[((size_t)h*NC_ + c)*D_ + d];
            vv = mem_v[((size_t)h*NC_ + c)*D_ + d];
        } else {
            int tok = s_ki[r-1];
            kv = kg[((size_t)bh*T_ + tok)*D_ + d];
            vv = vg[((size_t)bh*T_ + tok)*D_ + d];
        }
        s_k[i] = kv; s_v[i] = vv;
    }
    __syncthreads();
    const int rowi = tid >> 2, quad = tid & 3;
    const int tok = s_qi[rowi];
    const float* qr = qg + ((size_t)bh*T_ + tok)*D_ + quad*16;
    float qreg[16];
    #pragma unroll
    for (int i = 0; i < 16; i++) qreg[i] = qr[i];
    float m = -1e30f, l = 0.f, acc[16];
    #pragma unroll
    for (int i = 0; i < 16; i++) acc[i] = 0.f;
    for (int j = 0; j < 65; j++) {
        const float* krow = s_k + j*D_ + quad*16;
        float p = 0.f;
        #pragma unroll
        for (int i = 0; i < 16; i++) p += qreg[i] * krow[i];
        p += __shfl_xor(p, 1);
        p += __shfl_xor(p, 2);
        float s = p * 0.125f;
        float nm = fmaxf(m, s);
        float eo = __expf(m - nm);
        float en = __expf(s - nm);
        l = l * eo + en;
        const float* vrow = s_v + j*D_ + quad*16;
        #pragma unroll
        for (int i = 0; i < 16; i++) acc[i] = acc[i]*eo + en*vrow[i];
        m = nm;
    }
    float rl = 1.f / l;
    // dense store: bo[((bh*NC + c)*WSZ + rowi)*64 + quad*16 ...]
    float* orow = bo + (((size_t)bh*NC_ + c)*WSZ_ + rowi)*D_ + quad*16;
    #pragma unroll
    for (int i4 = 0; i4 < 4; i4++) {
        float4 st = { acc[i4*4+0]*rl, acc[i4*4+1]*rl, acc[i4*4+2]*rl, acc[i4*4+3]*rl };
        *(float4*)(orow + i4*4) = st;
    }
}

// ---------------- Kernel E: gather + divide + aux ----------------
__global__ __launch_bounds__(256) void gather_kernel(
    const float* __restrict__ bo, const u16* __restrict__ entries,
    const int* __restrict__ offsets, const int* __restrict__ counts,
    const double* __restrict__ aux_sum, float* __restrict__ out)
{
    const int tid = threadIdx.x;
    const int g = blockIdx.x * 4 + (tid >> 6);      // bh*T + tok
    const int lane = tid & 63;
    const int bh = g >> 13;
    const int start = offsets[g];
    const int len = counts[g];
    float sum = 0.f;
    for (int e = 0; e < len; e++) {
        int ent = entries[start + e];
        sum += bo[(((size_t)bh << 13) | (unsigned)ent) * D_ + lane];
    }
    out[(size_t)g * D_ + lane] = sum / ((float)len + 1e-5f);
    if (blockIdx.x == 0 && tid == 0)
        out[(size_t)BH * T_ * D_] = (float)(aux_sum[0] * (0.0001 / 33554432.0));
}

extern "C" void kernel_launch(void* const* d_in, const int* in_sizes, int n_in,
                              void* d_out, int out_size, void* d_ws, size_t ws_size,
                              hipStream_t stream)
{
    const float* q      = (const float*)d_in[0];
    const float* k      = (const float*)d_in[1];
    const float* v      = (const float*)d_in[2];
    const float* means  = (const float*)d_in[3];
    const float* mem_k  = (const float*)d_in[4];
    const float* mem_v  = (const float*)d_in[5];
    float* out = (float*)d_out;

    char* ws = (char*)d_ws;
    const size_t SZ_TOK = (size_t)BH * T_ * sizeof(int);          // 1 MiB
    const size_t SZ_IDX = (size_t)BH * NC_ * WSZ_ * sizeof(int);  // 1 MiB
    size_t off = 256;                                             // [0,256): aux double
    const size_t o_counts  = off; off += SZ_TOK;
    const size_t o_offsets = off; off += SZ_TOK;
    const size_t o_cursor  = off; off += SZ_TOK;
    const size_t o_entries = off; off += (size_t)BH * NC_ * WSZ_ * sizeof(u16);
    const size_t o_idxq    = off; off += SZ_IDX;
    const size_t o_idxk    = off; off += SZ_IDX;
    size_t o_bo = (off + 255) & ~(size_t)255;
    off = o_bo + (size_t)BH * NC_ * WSZ_ * D_ * sizeof(float);    // 64 MiB
    size_t o_dbuf = (off + 255) & ~(size_t)255;

    double* aux   = (double*)ws;
    int* counts   = (int*)(ws + o_counts);
    int* offsets  = (int*)(ws + o_offsets);
    int* cursor   = (int*)(ws + o_cursor);
    u16* entries  = (u16*)(ws + o_entries);
    int* idxq     = (int*)(ws + o_idxq);
    int* idxk     = (int*)(ws + o_idxk);
    float* bo     = (float*)(ws + o_bo);
    u16* dbuf     = (u16*)(ws + o_dbuf);

    const size_t per_pair = (size_t)2 * NC_ * T_ * sizeof(u16);   // 4 MiB
    int CH = 32;
    while (CH > 1 && o_dbuf + (size_t)CH * per_pair > ws_size) CH >>= 1;

    hipMemsetAsync(ws, 0, o_offsets, stream);   // zero aux + counts

    for (int p0 = 0; p0 < BH; p0 += CH) {
        dim3 gA(256, CH);
        dist_kernel<<<gA, 256, 0, stream>>>(q, k, means, dbuf, aux, p0);
        dim3 gB(NC_, 2, CH);
        topk_kernel<<<gB, 256, 0, stream>>>(dbuf, q, k, means, idxq, idxk, p0);
    }
    count_kernel<<<dim3(BH * NC_ * WSZ_ / 256), 256, 0, stream>>>(idxq, counts);
    scan_kernel<<<dim3(BH), 256, 0, stream>>>(counts, offsets, cursor);
    fill_kernel<<<dim3(BH * NC_ * WSZ_ / 256), 256, 0, stream>>>(idxq, cursor, entries);
    attn_kernel<<<dim3(NC_, BH), 256, 0, stream>>>(q, k, v, mem_k, mem_v, idxq, idxk, bo);
    gather_kernel<<<dim3(BH * T_ / 4), 256, 0, stream>>>(bo, entries, offsets, counts, aux, out);
}

// Round 3
// 878.293 us; speedup vs baseline: 1.9422x; 1.0519x over previous
//
#include <hip/hip_runtime.h>
#include <math.h>
#include <stdint.h>

#define B_   4
#define H_   8
#define BH   32
#define T_   8192
#define D_   64
#define NC_  128
#define WSZ_ 64
#define CAND_CAP 512

typedef unsigned short u16;
typedef short frag8 __attribute__((ext_vector_type(8)));
typedef float floatx4 __attribute__((ext_vector_type(4)));

__device__ inline u16 f2bf(float f) {
    unsigned int u = __float_as_uint(f);
    unsigned int r = (u + 0x7fffu + ((u >> 16) & 1u)) >> 16;
    return (u16)r;
}

// ---------------- Kernel A: bf16 MFMA dists + aux loss ----------------
__global__ __launch_bounds__(256) void dist_kernel(
    const float* __restrict__ qg, const float* __restrict__ kg,
    const float* __restrict__ means, u16* __restrict__ dbuf,
    double* __restrict__ aux_sum, int pair0)
{
    __shared__ float s_x[64 * 64];       // normalized fp32 tokens
    __shared__ u16   s_xb[64 * 80];      // bf16, padded stride 80
    __shared__ u16   s_mb[128 * 80];     // bf16 means, padded
    __shared__ int   s_argc[64];
    __shared__ float s_aux;
    const int tid = threadIdx.x;
    const int bh = pair0 + blockIdx.y;
    const int h  = bh & 7;
    const int tok0 = blockIdx.x * 64;            // within [0, 2T)
    const int isK  = (tok0 >= T_) ? 1 : 0;
    const int tloc0 = isK ? tok0 - T_ : tok0;
    const float* src = isK ? kg : qg;

    if (tid == 0) s_aux = 0.f;
    const float* mh = means + (size_t)h * NC_ * D_;
    for (int i = tid; i < NC_ * D_; i += 256)
        s_mb[(i >> 6) * 80 + (i & 63)] = f2bf(mh[i]);
    const float* sp = src + ((size_t)bh * T_ + tloc0) * D_;
    for (int i = tid; i < 64 * D_; i += 256) s_x[i] = sp[i];
    __syncthreads();
    {
        const int row = tid >> 2, sub = tid & 3;
        float ss = 0.f;
        #pragma unroll
        for (int e = 0; e < 16; e++) { float vv = s_x[row*64 + sub*16 + e]; ss += vv*vv; }
        ss += __shfl_xor(ss, 1); ss += __shfl_xor(ss, 2);
        const float rn = 1.0f / fmaxf(sqrtf(ss), 1e-12f);
        #pragma unroll
        for (int e = 0; e < 16; e++) {
            float vv = s_x[row*64 + sub*16 + e] * rn;
            s_x[row*64 + sub*16 + e] = vv;
            s_xb[row*80 + sub*16 + e] = f2bf(vv);
        }
    }
    __syncthreads();
    {
        const int w = tid >> 6, lane = tid & 63;
        const int mrow = lane & 15, quad = lane >> 4;
        const frag8 a0 = *(const frag8*)&s_xb[(w*16 + mrow)*80 + quad*8];
        const frag8 a1 = *(const frag8*)&s_xb[(w*16 + mrow)*80 + 32 + quad*8];
        float bv[4]; int bc[4];
        #pragma unroll
        for (int r = 0; r < 4; r++) { bv[r] = -1e30f; bc[r] = 0; }
        const int tokw = w * 16 + quad * 4;
        for (int n = 0; n < 8; n++) {
            const frag8 b0 = *(const frag8*)&s_mb[(n*16 + mrow)*80 + quad*8];
            const frag8 b1 = *(const frag8*)&s_mb[(n*16 + mrow)*80 + 32 + quad*8];
            floatx4 acc = {0.f, 0.f, 0.f, 0.f};
            acc = __builtin_amdgcn_mfma_f32_16x16x32_bf16(a0, b0, acc, 0, 0, 0);
            acc = __builtin_amdgcn_mfma_f32_16x16x32_bf16(a1, b1, acc, 0, 0, 0);
            const int cc = n*16 + mrow;
            u16 o0 = f2bf(acc[0]), o1 = f2bf(acc[1]), o2 = f2bf(acc[2]), o3 = f2bf(acc[3]);
            uint2 pk; pk.x = (unsigned)o0 | ((unsigned)o1 << 16);
                      pk.y = (unsigned)o2 | ((unsigned)o3 << 16);
            *(uint2*)&dbuf[(((size_t)blockIdx.y*2 + isK)*NC_ + cc)*T_ + tloc0 + tokw] = pk;
            #pragma unroll
            for (int r = 0; r < 4; r++)
                if (acc[r] > bv[r]) { bv[r] = acc[r]; bc[r] = cc; }
        }
        #pragma unroll
        for (int m = 1; m < 16; m <<= 1) {
            #pragma unroll
            for (int r = 0; r < 4; r++) {
                float ov = __shfl_xor(bv[r], m);
                int   oc = __shfl_xor(bc[r], m);
                if (ov > bv[r] || (ov == bv[r] && oc < bc[r])) { bv[r] = ov; bc[r] = oc; }
            }
        }
        if (mrow == 0) {
            #pragma unroll
            for (int r = 0; r < 4; r++) s_argc[tokw + r] = bc[r];
        }
    }
    __syncthreads();
    {
        const int row = tid >> 2, sub = tid & 3;
        const int c = s_argc[row];
        const float* mr = means + ((size_t)h*NC_ + c)*D_ + sub*16;
        float rs = 0.f;
        #pragma unroll
        for (int e = 0; e < 16; e++) {
            float dd = s_x[row*64 + sub*16 + e] - mr[e];
            rs += dd*dd;
        }
        rs += __shfl_xor(rs, 1); rs += __shfl_xor(rs, 2);
        if (sub == 0) atomicAdd(&s_aux, rs);
    }
    __syncthreads();
    if (tid == 0) atomicAdd(aux_sum, (double)s_aux);
}

// ---------------- Kernel B: margined candidate select + fp64 exact rank-64 (no sort) ----------------
__global__ __launch_bounds__(256) void topk_kernel(
    const u16* __restrict__ dbuf, const float* __restrict__ qg,
    const float* __restrict__ kg, const float* __restrict__ means,
    int* __restrict__ idx_q, int* __restrict__ idx_k, int pair0)
{
    __shared__ int s_hist[4096];
    __shared__ int s_scan[256];
    __shared__ int s_B, s_cnt;
    __shared__ int s_cand[CAND_CAP];
    __shared__ unsigned long long s_key[CAND_CAP];
    __shared__ int s_tok[CAND_CAP];
    __shared__ double s_mean[64];

    const int tid = threadIdx.x;
    const int c = blockIdx.x, isK = blockIdx.y, pl = blockIdx.z;
    const int bh = pair0 + pl, h = bh & 7;
    const u16* row = dbuf + (((size_t)pl*2 + isK)*NC_ + c)*T_;

    for (int i = tid; i < 4096; i += 256) s_hist[i] = 0;
    if (tid < 64) s_mean[tid] = (double)means[((size_t)h*NC_ + c)*D_ + tid];
    __syncthreads();
    // vectorized load: thread t owns tokens [t*32, t*32+32)
    u16 vals[32];
    {
        const uint4* rv = (const uint4*)(row + tid * 32);
        #pragma unroll
        for (int j4 = 0; j4 < 4; j4++) {
            uint4 pk = rv[j4];
            unsigned int wd[4] = {pk.x, pk.y, pk.z, pk.w};
            #pragma unroll
            for (int w2 = 0; w2 < 4; w2++) {
                vals[j4*8 + w2*2 + 0] = (u16)(wd[w2] & 0xffffu);
                vals[j4*8 + w2*2 + 1] = (u16)(wd[w2] >> 16);
            }
        }
    }
    #pragma unroll
    for (int j = 0; j < 32; j++) {
        u16 u = vals[j];
        unsigned int s = (u & 0x8000u) ? (unsigned int)((~u) & 0xffffu) : (unsigned int)(u | 0x8000u);
        atomicAdd(&s_hist[s >> 4], 1);
    }
    __syncthreads();
    int cs = 0;
    #pragma unroll
    for (int b2 = 0; b2 < 16; b2++) cs += s_hist[tid*16 + b2];
    s_scan[tid] = cs;
    __syncthreads();
    for (int off = 1; off < 256; off <<= 1) {
        int add = (tid + off < 256) ? s_scan[tid + off] : 0;
        __syncthreads();
        s_scan[tid] += add;
        __syncthreads();
    }
    {
        int Tj = s_scan[tid];
        int Tn = (tid < 255) ? s_scan[tid + 1] : 0;
        if (Tj >= WSZ_ && Tn < WSZ_) {          // rank-64 bin lives in my 16-bin chunk
            int running = Tn, Bb = tid * 16;
            for (int b2 = tid*16 + 15; b2 >= tid*16; b2--) {
                running += s_hist[b2];
                if (running >= WSZ_) { Bb = b2; break; }
            }
            s_B = Bb;
        }
    }
    __syncthreads();
    int thr = s_B - 2; if (thr < 0) thr = 0;    // 2-bin margin (~0.25 abs) >> bf16+MFMA error
    for (;;) {
        if (tid == 0) s_cnt = 0;
        __syncthreads();
        #pragma unroll
        for (int j = 0; j < 32; j++) {
            u16 u = vals[j];
            unsigned int s = (u & 0x8000u) ? (unsigned int)((~u) & 0xffffu) : (unsigned int)(u | 0x8000u);
            if ((int)(s >> 4) >= thr) {
                int p = atomicAdd(&s_cnt, 1);
                if (p < CAND_CAP) s_cand[p] = tid*32 + j;
            }
        }
        __syncthreads();
        if (s_cnt <= CAND_CAP) break;
        thr++;
        __syncthreads();
    }
    const int M = s_cnt;                        // >= 64 by construction
    // fp64 exact recompute: 4 threads per candidate, float4 loads
    const float* src = isK ? kg : qg;
    {
        const int sub = tid & 3;
        for (int ci = (tid >> 2); ci < M; ci += 64) {
            const int tok = s_cand[ci];
            const float* xr = src + ((size_t)bh*T_ + tok)*D_ + sub*16;
            double dot = 0.0, ss = 0.0;
            #pragma unroll
            for (int e4 = 0; e4 < 4; e4++) {
                float4 xv4 = *(const float4*)(xr + e4*4);
                double x0 = (double)xv4.x, x1 = (double)xv4.y;
                double x2 = (double)xv4.z, x3 = (double)xv4.w;
                const double* mm = &s_mean[sub*16 + e4*4];
                dot += x0*mm[0] + x1*mm[1] + x2*mm[2] + x3*mm[3];
                ss  += x0*x0 + x1*x1 + x2*x2 + x3*x3;
            }
            dot += __shfl_xor(dot, 1); dot += __shfl_xor(dot, 2);
            ss  += __shfl_xor(ss, 1);  ss  += __shfl_xor(ss, 2);
            if (sub == 0) {
                double val = dot / fmax(sqrt(ss), 1e-12);
                unsigned long long u = (unsigned long long)__double_as_longlong(val);
                u = (u & 0x8000000000000000ull) ? ~u : (u | 0x8000000000000000ull);
                s_key[ci] = u;
                s_tok[ci] = tok;
            }
        }
    }
    __syncthreads();
    // rank-select: rank_p = #{j : (key_j,idx_j) > (key_p,idx_p)}; output order irrelevant
    int* dst = (isK ? idx_k : idx_q) + ((size_t)bh*NC_ + c)*WSZ_;
    for (int p = tid; p < M; p += 256) {
        unsigned long long kp = s_key[p];
        int ip = s_tok[p];
        int rank = 0;
        for (int j = 0; j < M; j++) {
            unsigned long long kj = s_key[j];   // broadcast read, conflict-free
            int ij = s_tok[j];
            if (kj > kp || (kj == kp && ij < ip)) rank++;
        }
        if (rank < WSZ_) dst[rank] = ip;
    }
}

// ---------------- Kernel C1: selection counts ----------------
__global__ __launch_bounds__(256) void count_kernel(
    const int* __restrict__ idx_q, int* __restrict__ counts)
{
    int i = blockIdx.x * 256 + threadIdx.x;   // 0 .. BH*NC*WSZ-1
    int bh = i >> 13;
    atomicAdd(&counts[bh * T_ + idx_q[i]], 1);
}

// ---------------- Kernel C2: per-bh exclusive scan of counts -> offsets, cursor ----------------
__global__ __launch_bounds__(256) void scan_kernel(
    const int* __restrict__ counts, int* __restrict__ offsets, int* __restrict__ cursor)
{
    __shared__ int s_tmp[256];
    const int tid = threadIdx.x, bh = blockIdx.x;
    const int base = bh * T_;
    int c[32], s = 0;
    #pragma unroll
    for (int j = 0; j < 32; j++) { c[j] = counts[base + tid*32 + j]; s += c[j]; }
    s_tmp[tid] = s;
    __syncthreads();
    for (int off = 1; off < 256; off <<= 1) {
        int add = (tid >= off) ? s_tmp[tid - off] : 0;
        __syncthreads();
        s_tmp[tid] += add;
        __syncthreads();
    }
    int running = s_tmp[tid] - s + bh * (NC_ * WSZ_);   // exclusive prefix + bh base
    #pragma unroll
    for (int j = 0; j < 32; j++) {
        offsets[base + tid*32 + j] = running;
        cursor [base + tid*32 + j] = running;
        running += c[j];
    }
}

// ---------------- Kernel C3: fill CSR entries ----------------
__global__ __launch_bounds__(256) void fill_kernel(
    const int* __restrict__ idx_q, int* __restrict__ cursor, u16* __restrict__ entries)
{
    int i = blockIdx.x * 256 + threadIdx.x;   // 0 .. BH*NC*WSZ-1
    int bh = i >> 13;
    int tok = idx_q[i];
    int pos = atomicAdd(&cursor[bh * T_ + tok], 1);
    entries[pos] = (u16)(i & 8191);           // c*WSZ + slot
}

// ---------------- Kernel D: per-cluster attention -> dense bo (no atomics) ----------------
__global__ __launch_bounds__(256) void attn_kernel(
    const float* __restrict__ qg, const float* __restrict__ kg, const float* __restrict__ vg,
    const float* __restrict__ mem_k, const float* __restrict__ mem_v,
    const int* __restrict__ idx_q, const int* __restrict__ idx_k,
    float* __restrict__ bo)
{
    __shared__ float s_k[65 * D_];
    __shared__ float s_v[65 * D_];
    __shared__ int s_qi[WSZ_], s_ki[WSZ_];
    const int tid = threadIdx.x;
    const int c = blockIdx.x, bh = blockIdx.y, h = bh & 7;
    const int* qi = idx_q + ((size_t)bh*NC_ + c)*WSZ_;
    const int* ki = idx_k + ((size_t)bh*NC_ + c)*WSZ_;
    if (tid < WSZ_) { s_qi[tid] = qi[tid]; s_ki[tid] = ki[tid]; }
    __syncthreads();
    for (int i = tid; i < 65 * D_; i += 256) {
        int r = i >> 6, d = i & 63;
        float kv, vv;
        if (r == 0) {
            kv = mem_k[((size_t)h*NC_ + c)*D_ + d];
            vv = mem_v[((size_t)h*NC_ + c)*D_ + d];
        } else {
            int tok = s_ki[r-1];
            kv = kg[((size_t)bh*T_ + tok)*D_ + d];
            vv = vg[((size_t)bh*T_ + tok)*D_ + d];
        }
        s_k[i] = kv; s_v[i] = vv;
    }
    __syncthreads();
    const int rowi = tid >> 2, quad = tid & 3;
    const int tok = s_qi[rowi];
    const float* qr = qg + ((size_t)bh*T_ + tok)*D_ + quad*16;
    float qreg[16];
    #pragma unroll
    for (int i = 0; i < 16; i++) qreg[i] = qr[i];
    float m = -1e30f, l = 0.f, acc[16];
    #pragma unroll
    for (int i = 0; i < 16; i++) acc[i] = 0.f;
    for (int j = 0; j < 65; j++) {
        const float* krow = s_k + j*D_ + quad*16;
        float p = 0.f;
        #pragma unroll
        for (int i = 0; i < 16; i++) p += qreg[i] * krow[i];
        p += __shfl_xor(p, 1);
        p += __shfl_xor(p, 2);
        float s = p * 0.125f;
        float nm = fmaxf(m, s);
        float eo = __expf(m - nm);
        float en = __expf(s - nm);
        l = l * eo + en;
        const float* vrow = s_v + j*D_ + quad*16;
        #pragma unroll
        for (int i = 0; i < 16; i++) acc[i] = acc[i]*eo + en*vrow[i];
        m = nm;
    }
    float rl = 1.f / l;
    float* orow = bo + (((size_t)bh*NC_ + c)*WSZ_ + rowi)*D_ + quad*16;
    #pragma unroll
    for (int i4 = 0; i4 < 4; i4++) {
        float4 st = { acc[i4*4+0]*rl, acc[i4*4+1]*rl, acc[i4*4+2]*rl, acc[i4*4+3]*rl };
        *(float4*)(orow + i4*4) = st;
    }
}

// ---------------- Kernel E: gather + divide + aux ----------------
__global__ __launch_bounds__(256) void gather_kernel(
    const float* __restrict__ bo, const u16* __restrict__ entries,
    const int* __restrict__ offsets, const int* __restrict__ counts,
    const double* __restrict__ aux_sum, float* __restrict__ out)
{
    const int tid = threadIdx.x;
    const int g = blockIdx.x * 4 + (tid >> 6);      // bh*T + tok
    const int lane = tid & 63;
    const int bh = g >> 13;
    const int start = offsets[g];
    const int len = counts[g];
    float sum = 0.f;
    for (int e = 0; e < len; e++) {
        int ent = entries[start + e];
        sum += bo[(((size_t)bh << 13) | (unsigned)ent) * D_ + lane];
    }
    out[(size_t)g * D_ + lane] = sum / ((float)len + 1e-5f);
    if (blockIdx.x == 0 && tid == 0)
        out[(size_t)BH * T_ * D_] = (float)(aux_sum[0] * (0.0001 / 33554432.0));
}

extern "C" void kernel_launch(void* const* d_in, const int* in_sizes, int n_in,
                              void* d_out, int out_size, void* d_ws, size_t ws_size,
                              hipStream_t stream)
{
    const float* q      = (const float*)d_in[0];
    const float* k      = (const float*)d_in[1];
    const float* v      = (const float*)d_in[2];
    const float* means  = (const float*)d_in[3];
    const float* mem_k  = (const float*)d_in[4];
    const float* mem_v  = (const float*)d_in[5];
    float* out = (float*)d_out;

    char* ws = (char*)d_ws;
    const size_t SZ_TOK = (size_t)BH * T_ * sizeof(int);          // 1 MiB
    const size_t SZ_IDX = (size_t)BH * NC_ * WSZ_ * sizeof(int);  // 1 MiB
    size_t off = 256;                                             // [0,256): aux double
    const size_t o_counts  = off; off += SZ_TOK;
    const size_t o_offsets = off; off += SZ_TOK;
    const size_t o_cursor  = off; off += SZ_TOK;
    const size_t o_entries = off; off += (size_t)BH * NC_ * WSZ_ * sizeof(u16);
    const size_t o_idxq    = off; off += SZ_IDX;
    const size_t o_idxk    = off; off += SZ_IDX;
    size_t o_bo = (off + 255) & ~(size_t)255;
    off = o_bo + (size_t)BH * NC_ * WSZ_ * D_ * sizeof(float);    // 64 MiB
    size_t o_dbuf = (off + 255) & ~(size_t)255;

    double* aux   = (double*)ws;
    int* counts   = (int*)(ws + o_counts);
    int* offsets  = (int*)(ws + o_offsets);
    int* cursor   = (int*)(ws + o_cursor);
    u16* entries  = (u16*)(ws + o_entries);
    int* idxq     = (int*)(ws + o_idxq);
    int* idxk     = (int*)(ws + o_idxk);
    float* bo     = (float*)(ws + o_bo);
    u16* dbuf     = (u16*)(ws + o_dbuf);

    const size_t per_pair = (size_t)2 * NC_ * T_ * sizeof(u16);   // 4 MiB
    int CH = 32;
    while (CH > 1 && o_dbuf + (size_t)CH * per_pair > ws_size) CH >>= 1;

    hipMemsetAsync(ws, 0, o_offsets, stream);   // zero aux + counts

    for (int p0 = 0; p0 < BH; p0 += CH) {
        dim3 gA(256, CH);
        dist_kernel<<<gA, 256, 0, stream>>>(q, k, means, dbuf, aux, p0);
        dim3 gB(NC_, 2, CH);
        topk_kernel<<<gB, 256, 0, stream>>>(dbuf, q, k, means, idxq, idxk, p0);
    }
    count_kernel<<<dim3(BH * NC_ * WSZ_ / 256), 256, 0, stream>>>(idxq, counts);
    scan_kernel<<<dim3(BH), 256, 0, stream>>>(counts, offsets, cursor);
    fill_kernel<<<dim3(BH * NC_ * WSZ_ / 256), 256, 0, stream>>>(idxq, cursor, entries);
    attn_kernel<<<dim3(NC_, BH), 256, 0, stream>>>(q, k, v, mem_k, mem_v, idxq, idxk, bo);
    gather_kernel<<<dim3(BH * T_ / 4), 256, 0, stream>>>(bo, entries, offsets, counts, aux, out);
}

// Round 4
// 705.870 us; speedup vs baseline: 2.4166x; 1.2443x over previous
//
#include <hip/hip_runtime.h>
#include <math.h>
#include <stdint.h>

#define B_   4
#define H_   8
#define BH   32
#define T_   8192
#define D_   64
#define NC_  128
#define WSZ_ 64
#define CAND_CAP 512

typedef unsigned short u16;
typedef short frag8 __attribute__((ext_vector_type(8)));
typedef float floatx4 __attribute__((ext_vector_type(4)));

__device__ inline u16 f2bf(float f) {
    unsigned int u = __float_as_uint(f);
    unsigned int r = (u + 0x7fffu + ((u >> 16) & 1u)) >> 16;
    return (u16)r;
}

// ---------------- Kernel A: bf16 MFMA dists + aux loss ----------------
__global__ __launch_bounds__(256) void dist_kernel(
    const float* __restrict__ qg, const float* __restrict__ kg,
    const float* __restrict__ means, u16* __restrict__ dbuf,
    double* __restrict__ aux_sum, int pair0)
{
    __shared__ float s_x[64 * 64];       // normalized fp32 tokens
    __shared__ u16   s_xb[64 * 80];      // bf16, padded stride 80
    __shared__ u16   s_mb[128 * 80];     // bf16 means, padded
    __shared__ int   s_argc[64];
    __shared__ float s_aux;
    const int tid = threadIdx.x;
    const int bh = pair0 + blockIdx.y;
    const int h  = bh & 7;
    const int tok0 = blockIdx.x * 64;            // within [0, 2T)
    const int isK  = (tok0 >= T_) ? 1 : 0;
    const int tloc0 = isK ? tok0 - T_ : tok0;
    const float* src = isK ? kg : qg;

    if (tid == 0) s_aux = 0.f;
    const float* mh = means + (size_t)h * NC_ * D_;
    for (int i = tid; i < NC_ * D_; i += 256)
        s_mb[(i >> 6) * 80 + (i & 63)] = f2bf(mh[i]);
    const float* sp = src + ((size_t)bh * T_ + tloc0) * D_;
    for (int i = tid; i < 64 * D_; i += 256) s_x[i] = sp[i];
    __syncthreads();
    {
        const int row = tid >> 2, sub = tid & 3;
        float ss = 0.f;
        #pragma unroll
        for (int e = 0; e < 16; e++) { float vv = s_x[row*64 + sub*16 + e]; ss += vv*vv; }
        ss += __shfl_xor(ss, 1); ss += __shfl_xor(ss, 2);
        const float rn = 1.0f / fmaxf(sqrtf(ss), 1e-12f);
        #pragma unroll
        for (int e = 0; e < 16; e++) {
            float vv = s_x[row*64 + sub*16 + e] * rn;
            s_x[row*64 + sub*16 + e] = vv;
            s_xb[row*80 + sub*16 + e] = f2bf(vv);
        }
    }
    __syncthreads();
    {
        const int w = tid >> 6, lane = tid & 63;
        const int mrow = lane & 15, quad = lane >> 4;
        const frag8 a0 = *(const frag8*)&s_xb[(w*16 + mrow)*80 + quad*8];
        const frag8 a1 = *(const frag8*)&s_xb[(w*16 + mrow)*80 + 32 + quad*8];
        float bv[4]; int bc[4];
        #pragma unroll
        for (int r = 0; r < 4; r++) { bv[r] = -1e30f; bc[r] = 0; }
        const int tokw = w * 16 + quad * 4;
        for (int n = 0; n < 8; n++) {
            const frag8 b0 = *(const frag8*)&s_mb[(n*16 + mrow)*80 + quad*8];
            const frag8 b1 = *(const frag8*)&s_mb[(n*16 + mrow)*80 + 32 + quad*8];
            floatx4 acc = {0.f, 0.f, 0.f, 0.f};
            acc = __builtin_amdgcn_mfma_f32_16x16x32_bf16(a0, b0, acc, 0, 0, 0);
            acc = __builtin_amdgcn_mfma_f32_16x16x32_bf16(a1, b1, acc, 0, 0, 0);
            const int cc = n*16 + mrow;
            u16 o0 = f2bf(acc[0]), o1 = f2bf(acc[1]), o2 = f2bf(acc[2]), o3 = f2bf(acc[3]);
            uint2 pk; pk.x = (unsigned)o0 | ((unsigned)o1 << 16);
                      pk.y = (unsigned)o2 | ((unsigned)o3 << 16);
            *(uint2*)&dbuf[(((size_t)blockIdx.y*2 + isK)*NC_ + cc)*T_ + tloc0 + tokw] = pk;
            #pragma unroll
            for (int r = 0; r < 4; r++)
                if (acc[r] > bv[r]) { bv[r] = acc[r]; bc[r] = cc; }
        }
        #pragma unroll
        for (int m = 1; m < 16; m <<= 1) {
            #pragma unroll
            for (int r = 0; r < 4; r++) {
                float ov = __shfl_xor(bv[r], m);
                int   oc = __shfl_xor(bc[r], m);
                if (ov > bv[r] || (ov == bv[r] && oc < bc[r])) { bv[r] = ov; bc[r] = oc; }
            }
        }
        if (mrow == 0) {
            #pragma unroll
            for (int r = 0; r < 4; r++) s_argc[tokw + r] = bc[r];
        }
    }
    __syncthreads();
    {
        const int row = tid >> 2, sub = tid & 3;
        const int c = s_argc[row];
        const float* mr = means + ((size_t)h*NC_ + c)*D_ + sub*16;
        float rs = 0.f;
        #pragma unroll
        for (int e = 0; e < 16; e++) {
            float dd = s_x[row*64 + sub*16 + e] - mr[e];
            rs += dd*dd;
        }
        rs += __shfl_xor(rs, 1); rs += __shfl_xor(rs, 2);
        if (sub == 0) atomicAdd(&s_aux, rs);
    }
    __syncthreads();
    if (tid == 0) atomicAdd(aux_sum, (double)s_aux);
}

// ---------------- Kernel B v3: packed histogram + shuffle suffix-scan + 1-bin margin ----------------
__global__ __launch_bounds__(256) void topk_kernel(
    const u16* __restrict__ dbuf, const float* __restrict__ qg,
    const float* __restrict__ kg, const float* __restrict__ means,
    int* __restrict__ idx_q, int* __restrict__ idx_k, int pair0)
{
    __shared__ int s_hist[2048];          // 4096 logical bins, 2x16-bit packed (max 8192 < 2^16)
    __shared__ int s_scan[256];
    __shared__ int s_wtot[4];
    __shared__ int s_B, s_cnt;
    __shared__ int s_cand[CAND_CAP];
    __shared__ unsigned long long s_key[CAND_CAP];
    __shared__ int s_tok[CAND_CAP];
    __shared__ double s_mean[64];

    const int tid = threadIdx.x;
    const int lane = tid & 63, w = tid >> 6;
    const int c = blockIdx.x, isK = blockIdx.y, pl = blockIdx.z;
    const int bh = pair0 + pl, h = bh & 7;
    const u16* row = dbuf + (((size_t)pl*2 + isK)*NC_ + c)*T_;

    for (int i = tid; i < 2048; i += 256) s_hist[i] = 0;
    if (tid < 64) s_mean[tid] = (double)means[((size_t)h*NC_ + c)*D_ + tid];
    __syncthreads();
    // vectorized load + monotone key transform once into registers
    u16 keys[32];
    {
        const uint4* rv = (const uint4*)(row + tid * 32);
        #pragma unroll
        for (int j4 = 0; j4 < 4; j4++) {
            uint4 pk = rv[j4];
            unsigned int wd[4] = {pk.x, pk.y, pk.z, pk.w};
            #pragma unroll
            for (int w2 = 0; w2 < 4; w2++) {
                u16 lo = (u16)(wd[w2] & 0xffffu), hi = (u16)(wd[w2] >> 16);
                keys[j4*8 + w2*2 + 0] = (lo & 0x8000u) ? (u16)(~lo) : (u16)(lo | 0x8000u);
                keys[j4*8 + w2*2 + 1] = (hi & 0x8000u) ? (u16)(~hi) : (u16)(hi | 0x8000u);
            }
        }
    }
    #pragma unroll
    for (int j = 0; j < 32; j++) {
        int b = keys[j] >> 4;
        atomicAdd(&s_hist[b >> 1], 1 << ((b & 1) * 16));
    }
    __syncthreads();
    // chunk sums (16 logical bins per thread) + wave shuffle suffix-scan (2 barriers total)
    int cs = 0;
    #pragma unroll
    for (int k2 = 0; k2 < 8; k2++) { int v2 = s_hist[tid*8 + k2]; cs += (v2 & 0xffff) + (v2 >> 16); }
    int sv = cs;
    #pragma unroll
    for (int off = 1; off < 64; off <<= 1) {
        int o = __shfl_down(sv, off);
        if (lane + off < 64) sv += o;
    }
    if (lane == 0) s_wtot[w] = sv;
    __syncthreads();
    {
        int add = 0;
        #pragma unroll
        for (int w2 = 0; w2 < 4; w2++) if (w2 > w) add += s_wtot[w2];
        s_scan[tid] = sv + add;
    }
    __syncthreads();
    {
        int Tj = s_scan[tid];
        int Tn = (tid < 255) ? s_scan[tid + 1] : 0;
        if (Tj >= WSZ_ && Tn < WSZ_) {          // rank-64 bin lives in my 16-bin chunk
            int running = Tn, Bb = tid * 16;
            for (int b2 = tid*16 + 15; b2 >= tid*16; b2--) {
                running += (s_hist[b2 >> 1] >> ((b2 & 1) * 16)) & 0xffff;
                if (running >= WSZ_) { Bb = b2; break; }
            }
            s_B = Bb;
        }
    }
    __syncthreads();
    int thr = s_B - 1; if (thr < 0) thr = 0;    // 1 bin >= 0.25 at cutoff >> 0.02 worst-case bf16/MFMA error
    for (;;) {
        if (tid == 0) s_cnt = 0;
        __syncthreads();
        #pragma unroll
        for (int j = 0; j < 32; j++) {
            if ((int)(keys[j] >> 4) >= thr) {
                int p = atomicAdd(&s_cnt, 1);
                if (p < CAND_CAP) s_cand[p] = tid*32 + j;
            }
        }
        __syncthreads();
        if (s_cnt <= CAND_CAP) break;
        thr++;
        __syncthreads();
    }
    const int M = s_cnt;                        // >= 64 by construction
    // fp64 exact recompute: 4 threads per candidate, float4 loads
    const float* src = isK ? kg : qg;
    {
        const int sub = tid & 3;
        for (int ci = (tid >> 2); ci < M; ci += 64) {
            const int tok = s_cand[ci];
            const float* xr = src + ((size_t)bh*T_ + tok)*D_ + sub*16;
            double dot = 0.0, ss = 0.0;
            #pragma unroll
            for (int e4 = 0; e4 < 4; e4++) {
                float4 xv4 = *(const float4*)(xr + e4*4);
                double x0 = (double)xv4.x, x1 = (double)xv4.y;
                double x2 = (double)xv4.z, x3 = (double)xv4.w;
                const double* mm = &s_mean[sub*16 + e4*4];
                dot += x0*mm[0] + x1*mm[1] + x2*mm[2] + x3*mm[3];
                ss  += x0*x0 + x1*x1 + x2*x2 + x3*x3;
            }
            dot += __shfl_xor(dot, 1); dot += __shfl_xor(dot, 2);
            ss  += __shfl_xor(ss, 1);  ss  += __shfl_xor(ss, 2);
            if (sub == 0) {
                double val = dot / fmax(sqrt(ss), 1e-12);
                unsigned long long u = (unsigned long long)__double_as_longlong(val);
                u = (u & 0x8000000000000000ull) ? ~u : (u | 0x8000000000000000ull);
                s_key[ci] = u;
                s_tok[ci] = tok;
            }
        }
    }
    __syncthreads();
    // rank-select: rank_p = #{j : (key_j,idx_j) > (key_p,idx_p)}; output order irrelevant
    int* dst = (isK ? idx_k : idx_q) + ((size_t)bh*NC_ + c)*WSZ_;
    for (int p = tid; p < M; p += 256) {
        unsigned long long kp = s_key[p];
        int ip = s_tok[p];
        int rank = 0;
        for (int j = 0; j < M; j++) {
            unsigned long long kj = s_key[j];   // broadcast read, conflict-free
            int ij = s_tok[j];
            if (kj > kp || (kj == kp && ij < ip)) rank++;
        }
        if (rank < WSZ_) dst[rank] = ip;
    }
}

// ---------------- Kernel C1: selection counts ----------------
__global__ __launch_bounds__(256) void count_kernel(
    const int* __restrict__ idx_q, int* __restrict__ counts)
{
    int i = blockIdx.x * 256 + threadIdx.x;   // 0 .. BH*NC*WSZ-1
    int bh = i >> 13;
    atomicAdd(&counts[bh * T_ + idx_q[i]], 1);
}

// ---------------- Kernel C2: per-bh exclusive scan of counts -> offsets, cursor ----------------
__global__ __launch_bounds__(256) void scan_kernel(
    const int* __restrict__ counts, int* __restrict__ offsets, int* __restrict__ cursor)
{
    __shared__ int s_tmp[256];
    const int tid = threadIdx.x, bh = blockIdx.x;
    const int base = bh * T_;
    int c[32], s = 0;
    #pragma unroll
    for (int j = 0; j < 32; j++) { c[j] = counts[base + tid*32 + j]; s += c[j]; }
    s_tmp[tid] = s;
    __syncthreads();
    for (int off = 1; off < 256; off <<= 1) {
        int add = (tid >= off) ? s_tmp[tid - off] : 0;
        __syncthreads();
        s_tmp[tid] += add;
        __syncthreads();
    }
    int running = s_tmp[tid] - s + bh * (NC_ * WSZ_);   // exclusive prefix + bh base
    #pragma unroll
    for (int j = 0; j < 32; j++) {
        offsets[base + tid*32 + j] = running;
        cursor [base + tid*32 + j] = running;
        running += c[j];
    }
}

// ---------------- Kernel C3: fill CSR entries ----------------
__global__ __launch_bounds__(256) void fill_kernel(
    const int* __restrict__ idx_q, int* __restrict__ cursor, u16* __restrict__ entries)
{
    int i = blockIdx.x * 256 + threadIdx.x;   // 0 .. BH*NC*WSZ-1
    int bh = i >> 13;
    int tok = idx_q[i];
    int pos = atomicAdd(&cursor[bh * T_ + tok], 1);
    entries[pos] = (u16)(i & 8191);           // c*WSZ + slot
}

// ---------------- Kernel D: per-cluster attention -> dense bo (no atomics) ----------------
__global__ __launch_bounds__(256) void attn_kernel(
    const float* __restrict__ qg, const float* __restrict__ kg, const float* __restrict__ vg,
    const float* __restrict__ mem_k, const float* __restrict__ mem_v,
    const int* __restrict__ idx_q, const int* __restrict__ idx_k,
    float* __restrict__ bo)
{
    __shared__ float s_k[65 * D_];
    __shared__ float s_v[65 * D_];
    __shared__ int s_qi[WSZ_], s_ki[WSZ_];
    const int tid = threadIdx.x;
    const int c = blockIdx.x, bh = blockIdx.y, h = bh & 7;
    const int* qi = idx_q + ((size_t)bh*NC_ + c)*WSZ_;
    const int* ki = idx_k + ((size_t)bh*NC_ + c)*WSZ_;
    if (tid < WSZ_) { s_qi[tid] = qi[tid]; s_ki[tid] = ki[tid]; }
    __syncthreads();
    for (int i = tid; i < 65 * D_; i += 256) {
        int r = i >> 6, d = i & 63;
        float kv, vv;
        if (r == 0) {
            kv = mem_k[((size_t)h*NC_ + c)*D_ + d];
            vv = mem_v[((size_t)h*NC_ + c)*D_ + d];
        } else {
            int tok = s_ki[r-1];
            kv = kg[((size_t)bh*T_ + tok)*D_ + d];
            vv = vg[((size_t)bh*T_ + tok)*D_ + d];
        }
        s_k[i] = kv; s_v[i] = vv;
    }
    __syncthreads();
    const int rowi = tid >> 2, quad = tid & 3;
    const int tok = s_qi[rowi];
    const float* qr = qg + ((size_t)bh*T_ + tok)*D_ + quad*16;
    float qreg[16];
    #pragma unroll
    for (int i = 0; i < 16; i++) qreg[i] = qr[i];
    float m = -1e30f, l = 0.f, acc[16];
    #pragma unroll
    for (int i = 0; i < 16; i++) acc[i] = 0.f;
    for (int j = 0; j < 65; j++) {
        const float* krow = s_k + j*D_ + quad*16;
        float p = 0.f;
        #pragma unroll
        for (int i = 0; i < 16; i++) p += qreg[i] * krow[i];
        p += __shfl_xor(p, 1);
        p += __shfl_xor(p, 2);
        float s = p * 0.125f;
        float nm = fmaxf(m, s);
        float eo = __expf(m - nm);
        float en = __expf(s - nm);
        l = l * eo + en;
        const float* vrow = s_v + j*D_ + quad*16;
        #pragma unroll
        for (int i = 0; i < 16; i++) acc[i] = acc[i]*eo + en*vrow[i];
        m = nm;
    }
    float rl = 1.f / l;
    float* orow = bo + (((size_t)bh*NC_ + c)*WSZ_ + rowi)*D_ + quad*16;
    #pragma unroll
    for (int i4 = 0; i4 < 4; i4++) {
        float4 st = { acc[i4*4+0]*rl, acc[i4*4+1]*rl, acc[i4*4+2]*rl, acc[i4*4+3]*rl };
        *(float4*)(orow + i4*4) = st;
    }
}

// ---------------- Kernel E: gather + divide + aux ----------------
__global__ __launch_bounds__(256) void gather_kernel(
    const float* __restrict__ bo, const u16* __restrict__ entries,
    const int* __restrict__ offsets, const int* __restrict__ counts,
    const double* __restrict__ aux_sum, float* __restrict__ out)
{
    const int tid = threadIdx.x;
    const int g = blockIdx.x * 4 + (tid >> 6);      // bh*T + tok
    const int lane = tid & 63;
    const int bh = g >> 13;
    const int start = offsets[g];
    const int len = counts[g];
    float sum = 0.f;
    for (int e = 0; e < len; e++) {
        int ent = entries[start + e];
        sum += bo[(((size_t)bh << 13) | (unsigned)ent) * D_ + lane];
    }
    out[(size_t)g * D_ + lane] = sum / ((float)len + 1e-5f);
    if (blockIdx.x == 0 && tid == 0)
        out[(size_t)BH * T_ * D_] = (float)(aux_sum[0] * (0.0001 / 33554432.0));
}

extern "C" void kernel_launch(void* const* d_in, const int* in_sizes, int n_in,
                              void* d_out, int out_size, void* d_ws, size_t ws_size,
                              hipStream_t stream)
{
    const float* q      = (const float*)d_in[0];
    const float* k      = (const float*)d_in[1];
    const float* v      = (const float*)d_in[2];
    const float* means  = (const float*)d_in[3];
    const float* mem_k  = (const float*)d_in[4];
    const float* mem_v  = (const float*)d_in[5];
    float* out = (float*)d_out;

    char* ws = (char*)d_ws;
    const size_t SZ_TOK = (size_t)BH * T_ * sizeof(int);          // 1 MiB
    const size_t SZ_IDX = (size_t)BH * NC_ * WSZ_ * sizeof(int);  // 1 MiB
    size_t off = 256;                                             // [0,256): aux double
    const size_t o_counts  = off; off += SZ_TOK;
    const size_t o_offsets = off; off += SZ_TOK;
    const size_t o_cursor  = off; off += SZ_TOK;
    const size_t o_entries = off; off += (size_t)BH * NC_ * WSZ_ * sizeof(u16);
    const size_t o_idxq    = off; off += SZ_IDX;
    const size_t o_idxk    = off; off += SZ_IDX;
    size_t o_bo = (off + 255) & ~(size_t)255;
    off = o_bo + (size_t)BH * NC_ * WSZ_ * D_ * sizeof(float);    // 64 MiB
    size_t o_dbuf = (off + 255) & ~(size_t)255;

    double* aux   = (double*)ws;
    int* counts   = (int*)(ws + o_counts);
    int* offsets  = (int*)(ws + o_offsets);
    int* cursor   = (int*)(ws + o_cursor);
    u16* entries  = (u16*)(ws + o_entries);
    int* idxq     = (int*)(ws + o_idxq);
    int* idxk     = (int*)(ws + o_idxk);
    float* bo     = (float*)(ws + o_bo);
    u16* dbuf     = (u16*)(ws + o_dbuf);

    const size_t per_pair = (size_t)2 * NC_ * T_ * sizeof(u16);   // 4 MiB
    int CH = 32;
    while (CH > 1 && o_dbuf + (size_t)CH * per_pair > ws_size) CH >>= 1;

    hipMemsetAsync(ws, 0, o_offsets, stream);   // zero aux + counts

    for (int p0 = 0; p0 < BH; p0 += CH) {
        dim3 gA(256, CH);
        dist_kernel<<<gA, 256, 0, stream>>>(q, k, means, dbuf, aux, p0);
        dim3 gB(NC_, 2, CH);
        topk_kernel<<<gB, 256, 0, stream>>>(dbuf, q, k, means, idxq, idxk, p0);
    }
    count_kernel<<<dim3(BH * NC_ * WSZ_ / 256), 256, 0, stream>>>(idxq, counts);
    scan_kernel<<<dim3(BH), 256, 0, stream>>>(counts, offsets, cursor);
    fill_kernel<<<dim3(BH * NC_ * WSZ_ / 256), 256, 0, stream>>>(idxq, cursor, entries);
    attn_kernel<<<dim3(NC_, BH), 256, 0, stream>>>(q, k, v, mem_k, mem_v, idxq, idxk, bo);
    gather_kernel<<<dim3(BH * T_ / 4), 256, 0, stream>>>(bo, entries, offsets, counts, aux, out);
}

// Round 5
// 649.871 us; speedup vs baseline: 2.6249x; 1.0862x over previous
//
#include <hip/hip_runtime.h>
#include <math.h>
#include <stdint.h>

#define B_   4
#define H_   8
#define BH   32
#define T_   8192
#define D_   64
#define NC_  128
#define WSZ_ 64
#define CAND_CAP 512

typedef unsigned short u16;
typedef short frag8 __attribute__((ext_vector_type(8)));
typedef float floatx4 __attribute__((ext_vector_type(4)));

__device__ inline u16 f2bf(float f) {
    unsigned int u = __float_as_uint(f);
    unsigned int r = (u + 0x7fffu + ((u >> 16) & 1u)) >> 16;
    return (u16)r;
}
__device__ inline unsigned pack2(float a, float b) {
    return (unsigned)f2bf(a) | ((unsigned)f2bf(b) << 16);
}

// ---------------- Kernel A v2: regs-only normalize + LDS-staged coalesced dbuf write ----------------
// LDS: s_mb 18.0 KiB + s_ov 17.0 KiB + misc ~0.3 KiB = ~36.3 KiB -> 4 blocks/CU
__global__ __launch_bounds__(256, 4) void dist_kernel(
    const float* __restrict__ qg, const float* __restrict__ kg,
    const float* __restrict__ means, u16* __restrict__ dbuf,
    double* __restrict__ aux_sum, int pair0)
{
    __shared__ u16 s_mb[128 * 72];       // bf16 means, stride 72 (2-way-free on b128)
    __shared__ u16 s_ov[128 * 68];       // overlay: xb (64 x stride 72) then C-stage (128 x stride 68)
    __shared__ int s_argc[64];
    __shared__ float s_aux;
    const int tid = threadIdx.x;
    const int bh = pair0 + blockIdx.y;
    const int h  = bh & 7;
    const int tok0 = blockIdx.x * 64;            // within [0, 2T)
    const int isK  = (tok0 >= T_) ? 1 : 0;
    const int tloc0 = isK ? tok0 - T_ : tok0;
    const float* src = isK ? kg : qg;

    if (tid == 0) s_aux = 0.f;
    // means -> LDS bf16 (vectorized float4 -> uint2)
    {
        const float* mh = means + (size_t)h * NC_ * D_;
        #pragma unroll
        for (int it = 0; it < 8; it++) {
            int i = it * 1024 + tid * 4;
            float4 mv = *(const float4*)(mh + i);
            uint2 pk = { pack2(mv.x, mv.y), pack2(mv.z, mv.w) };
            *(uint2*)&s_mb[(i >> 6) * 72 + (i & 63)] = pk;
        }
    }
    // token row -> registers, normalize in regs, bf16 slice -> xb (own-wave rows only)
    const int row = tid >> 2, sub = tid & 3;
    float xr[16];
    {
        const float* sp = src + ((size_t)bh * T_ + tloc0 + row) * D_ + sub * 16;
        #pragma unroll
        for (int e4 = 0; e4 < 4; e4++) {
            float4 xv = *(const float4*)(sp + e4 * 4);
            xr[e4*4+0] = xv.x; xr[e4*4+1] = xv.y; xr[e4*4+2] = xv.z; xr[e4*4+3] = xv.w;
        }
        float ss = 0.f;
        #pragma unroll
        for (int e = 0; e < 16; e++) ss += xr[e] * xr[e];
        ss += __shfl_xor(ss, 1); ss += __shfl_xor(ss, 2);
        const float rn = 1.0f / fmaxf(sqrtf(ss), 1e-12f);
        #pragma unroll
        for (int e = 0; e < 16; e++) xr[e] *= rn;
        uint4 p0 = { pack2(xr[0],xr[1]), pack2(xr[2],xr[3]), pack2(xr[4],xr[5]), pack2(xr[6],xr[7]) };
        uint4 p1 = { pack2(xr[8],xr[9]), pack2(xr[10],xr[11]), pack2(xr[12],xr[13]), pack2(xr[14],xr[15]) };
        *(uint4*)&s_ov[row * 72 + sub * 16]     = p0;
        *(uint4*)&s_ov[row * 72 + sub * 16 + 8] = p1;
    }
    __syncthreads();                               // mb + xb visible
    const int w = tid >> 6, lane = tid & 63;
    const int mrow = lane & 15, quad = lane >> 4;
    const frag8 a0 = *(const frag8*)&s_ov[(w*16 + mrow)*72 + quad*8];
    const frag8 a1 = *(const frag8*)&s_ov[(w*16 + mrow)*72 + 32 + quad*8];
    __syncthreads();                               // all a-frag reads done before stage overwrite
    {
        float bv[4]; int bc[4];
        #pragma unroll
        for (int r = 0; r < 4; r++) { bv[r] = -1e30f; bc[r] = 0; }
        const int tokw = w * 16 + quad * 4;        // block-local token base of my C rows
        #pragma unroll
        for (int n = 0; n < 8; n++) {
            const frag8 b0 = *(const frag8*)&s_mb[(n*16 + mrow)*72 + quad*8];
            const frag8 b1 = *(const frag8*)&s_mb[(n*16 + mrow)*72 + 32 + quad*8];
            floatx4 acc = {0.f, 0.f, 0.f, 0.f};
            acc = __builtin_amdgcn_mfma_f32_16x16x32_bf16(a0, b0, acc, 0, 0, 0);
            acc = __builtin_amdgcn_mfma_f32_16x16x32_bf16(a1, b1, acc, 0, 0, 0);
            const int cc = n*16 + mrow;            // cluster (C col = lane&15)
            uint2 pk = { pack2(acc[0], acc[1]), pack2(acc[2], acc[3]) };
            *(uint2*)&s_ov[cc * 68 + tokw] = pk;   // stage, conflict-light
            #pragma unroll
            for (int r = 0; r < 4; r++)
                if (acc[r] > bv[r]) { bv[r] = acc[r]; bc[r] = cc; }   // n asc => lowest c on ties
        }
        #pragma unroll
        for (int m = 1; m < 16; m <<= 1) {
            #pragma unroll
            for (int r = 0; r < 4; r++) {
                float ov = __shfl_xor(bv[r], m);
                int   oc = __shfl_xor(bc[r], m);
                if (ov > bv[r] || (ov == bv[r] && oc < bc[r])) { bv[r] = ov; bc[r] = oc; }
            }
        }
        if (mrow == 0) {
            #pragma unroll
            for (int r = 0; r < 4; r++) s_argc[tokw + r] = bc[r];
        }
    }
    __syncthreads();                               // stage + argc visible
    // coalesced dbuf writeout: 16 lanes cover one 128 B cluster-row segment
    {
        const size_t dbase = ((size_t)blockIdx.y*2 + isK) * NC_;
        #pragma unroll
        for (int it = 0; it < 8; it++) {
            int idx = it * 256 + tid;              // 0..2047
            int crow = idx >> 4;                   // cluster 0..127
            int colg = (idx & 15) * 4;             // token 0..60 step 4
            uint2 pk = *(const uint2*)&s_ov[crow * 68 + colg];
            *(uint2*)&dbuf[(dbase + crow) * T_ + tloc0 + colg] = pk;
        }
    }
    // aux residual from registers (same thread<->row mapping)
    {
        const int c = s_argc[row];
        const float* mr = means + ((size_t)h*NC_ + c)*D_ + sub*16;
        float rs = 0.f;
        #pragma unroll
        for (int e4 = 0; e4 < 4; e4++) {
            float4 mv = *(const float4*)(mr + e4*4);
            float d0 = xr[e4*4+0]-mv.x, d1 = xr[e4*4+1]-mv.y;
            float d2 = xr[e4*4+2]-mv.z, d3 = xr[e4*4+3]-mv.w;
            rs += d0*d0 + d1*d1 + d2*d2 + d3*d3;
        }
        rs += __shfl_xor(rs, 1); rs += __shfl_xor(rs, 2);
        if (sub == 0) atomicAdd(&s_aux, rs);
    }
    __syncthreads();
    if (tid == 0) atomicAdd(aux_sum, (double)s_aux);
}

// ---------------- Kernel B: packed histogram + shuffle suffix-scan + 1-bin margin ----------------
__global__ __launch_bounds__(256) void topk_kernel(
    const u16* __restrict__ dbuf, const float* __restrict__ qg,
    const float* __restrict__ kg, const float* __restrict__ means,
    int* __restrict__ idx_q, int* __restrict__ idx_k, int pair0)
{
    __shared__ int s_hist[2048];          // 4096 logical bins, 2x16-bit packed
    __shared__ int s_scan[256];
    __shared__ int s_wtot[4];
    __shared__ int s_B, s_cnt;
    __shared__ int s_cand[CAND_CAP];
    __shared__ unsigned long long s_key[CAND_CAP];
    __shared__ int s_tok[CAND_CAP];
    __shared__ double s_mean[64];

    const int tid = threadIdx.x;
    const int lane = tid & 63, w = tid >> 6;
    const int c = blockIdx.x, isK = blockIdx.y, pl = blockIdx.z;
    const int bh = pair0 + pl, h = bh & 7;
    const u16* row = dbuf + (((size_t)pl*2 + isK)*NC_ + c)*T_;

    for (int i = tid; i < 2048; i += 256) s_hist[i] = 0;
    if (tid < 64) s_mean[tid] = (double)means[((size_t)h*NC_ + c)*D_ + tid];
    __syncthreads();
    u16 keys[32];
    {
        const uint4* rv = (const uint4*)(row + tid * 32);
        #pragma unroll
        for (int j4 = 0; j4 < 4; j4++) {
            uint4 pk = rv[j4];
            unsigned int wd[4] = {pk.x, pk.y, pk.z, pk.w};
            #pragma unroll
            for (int w2 = 0; w2 < 4; w2++) {
                u16 lo = (u16)(wd[w2] & 0xffffu), hi = (u16)(wd[w2] >> 16);
                keys[j4*8 + w2*2 + 0] = (lo & 0x8000u) ? (u16)(~lo) : (u16)(lo | 0x8000u);
                keys[j4*8 + w2*2 + 1] = (hi & 0x8000u) ? (u16)(~hi) : (u16)(hi | 0x8000u);
            }
        }
    }
    #pragma unroll
    for (int j = 0; j < 32; j++) {
        int b = keys[j] >> 4;
        atomicAdd(&s_hist[b >> 1], 1 << ((b & 1) * 16));
    }
    __syncthreads();
    int cs = 0;
    #pragma unroll
    for (int k2 = 0; k2 < 8; k2++) { int v2 = s_hist[tid*8 + k2]; cs += (v2 & 0xffff) + (v2 >> 16); }
    int sv = cs;
    #pragma unroll
    for (int off = 1; off < 64; off <<= 1) {
        int o = __shfl_down(sv, off);
        if (lane + off < 64) sv += o;
    }
    if (lane == 0) s_wtot[w] = sv;
    __syncthreads();
    {
        int add = 0;
        #pragma unroll
        for (int w2 = 0; w2 < 4; w2++) if (w2 > w) add += s_wtot[w2];
        s_scan[tid] = sv + add;
    }
    __syncthreads();
    {
        int Tj = s_scan[tid];
        int Tn = (tid < 255) ? s_scan[tid + 1] : 0;
        if (Tj >= WSZ_ && Tn < WSZ_) {
            int running = Tn, Bb = tid * 16;
            for (int b2 = tid*16 + 15; b2 >= tid*16; b2--) {
                running += (s_hist[b2 >> 1] >> ((b2 & 1) * 16)) & 0xffff;
                if (running >= WSZ_) { Bb = b2; break; }
            }
            s_B = Bb;
        }
    }
    __syncthreads();
    int thr = s_B - 1; if (thr < 0) thr = 0;    // 1 bin >= 0.25 at cutoff >> 0.02 worst-case bf16/MFMA error
    for (;;) {
        if (tid == 0) s_cnt = 0;
        __syncthreads();
        #pragma unroll
        for (int j = 0; j < 32; j++) {
            if ((int)(keys[j] >> 4) >= thr) {
                int p = atomicAdd(&s_cnt, 1);
                if (p < CAND_CAP) s_cand[p] = tid*32 + j;
            }
        }
        __syncthreads();
        if (s_cnt <= CAND_CAP) break;
        thr++;
        __syncthreads();
    }
    const int M = s_cnt;                        // >= 64 by construction
    const float* src = isK ? kg : qg;
    {
        const int sub = tid & 3;
        for (int ci = (tid >> 2); ci < M; ci += 64) {
            const int tok = s_cand[ci];
            const float* xr = src + ((size_t)bh*T_ + tok)*D_ + sub*16;
            double dot = 0.0, ss = 0.0;
            #pragma unroll
            for (int e4 = 0; e4 < 4; e4++) {
                float4 xv4 = *(const float4*)(xr + e4*4);
                double x0 = (double)xv4.x, x1 = (double)xv4.y;
                double x2 = (double)xv4.z, x3 = (double)xv4.w;
                const double* mm = &s_mean[sub*16 + e4*4];
                dot += x0*mm[0] + x1*mm[1] + x2*mm[2] + x3*mm[3];
                ss  += x0*x0 + x1*x1 + x2*x2 + x3*x3;
            }
            dot += __shfl_xor(dot, 1); dot += __shfl_xor(dot, 2);
            ss  += __shfl_xor(ss, 1);  ss  += __shfl_xor(ss, 2);
            if (sub == 0) {
                double val = dot / fmax(sqrt(ss), 1e-12);
                unsigned long long u = (unsigned long long)__double_as_longlong(val);
                u = (u & 0x8000000000000000ull) ? ~u : (u | 0x8000000000000000ull);
                s_key[ci] = u;
                s_tok[ci] = tok;
            }
        }
    }
    __syncthreads();
    int* dst = (isK ? idx_k : idx_q) + ((size_t)bh*NC_ + c)*WSZ_;
    for (int p = tid; p < M; p += 256) {
        unsigned long long kp = s_key[p];
        int ip = s_tok[p];
        int rank = 0;
        for (int j = 0; j < M; j++) {
            unsigned long long kj = s_key[j];
            int ij = s_tok[j];
            if (kj > kp || (kj == kp && ij < ip)) rank++;
        }
        if (rank < WSZ_) dst[rank] = ip;
    }
}

// ---------------- Kernel C1: selection counts ----------------
__global__ __launch_bounds__(256) void count_kernel(
    const int* __restrict__ idx_q, int* __restrict__ counts)
{
    int i = blockIdx.x * 256 + threadIdx.x;   // 0 .. BH*NC*WSZ-1
    int bh = i >> 13;
    atomicAdd(&counts[bh * T_ + idx_q[i]], 1);
}

// ---------------- Kernel C2: per-bh exclusive scan of counts -> offsets, cursor ----------------
__global__ __launch_bounds__(256) void scan_kernel(
    const int* __restrict__ counts, int* __restrict__ offsets, int* __restrict__ cursor)
{
    __shared__ int s_tmp[256];
    const int tid = threadIdx.x, bh = blockIdx.x;
    const int base = bh * T_;
    int c[32], s = 0;
    #pragma unroll
    for (int j = 0; j < 32; j++) { c[j] = counts[base + tid*32 + j]; s += c[j]; }
    s_tmp[tid] = s;
    __syncthreads();
    for (int off = 1; off < 256; off <<= 1) {
        int add = (tid >= off) ? s_tmp[tid - off] : 0;
        __syncthreads();
        s_tmp[tid] += add;
        __syncthreads();
    }
    int running = s_tmp[tid] - s + bh * (NC_ * WSZ_);   // exclusive prefix + bh base
    #pragma unroll
    for (int j = 0; j < 32; j++) {
        offsets[base + tid*32 + j] = running;
        cursor [base + tid*32 + j] = running;
        running += c[j];
    }
}

// ---------------- Kernel C3: fill CSR entries ----------------
__global__ __launch_bounds__(256) void fill_kernel(
    const int* __restrict__ idx_q, int* __restrict__ cursor, u16* __restrict__ entries)
{
    int i = blockIdx.x * 256 + threadIdx.x;   // 0 .. BH*NC*WSZ-1
    int bh = i >> 13;
    int tok = idx_q[i];
    int pos = atomicAdd(&cursor[bh * T_ + tok], 1);
    entries[pos] = (u16)(i & 8191);           // c*WSZ + slot
}

// ---------------- Kernel D: per-cluster attention -> dense bo (no atomics) ----------------
__global__ __launch_bounds__(256) void attn_kernel(
    const float* __restrict__ qg, const float* __restrict__ kg, const float* __restrict__ vg,
    const float* __restrict__ mem_k, const float* __restrict__ mem_v,
    const int* __restrict__ idx_q, const int* __restrict__ idx_k,
    float* __restrict__ bo)
{
    __shared__ float s_k[65 * D_];
    __shared__ float s_v[65 * D_];
    __shared__ int s_qi[WSZ_], s_ki[WSZ_];
    const int tid = threadIdx.x;
    const int c = blockIdx.x, bh = blockIdx.y, h = bh & 7;
    const int* qi = idx_q + ((size_t)bh*NC_ + c)*WSZ_;
    const int* ki = idx_k + ((size_t)bh*NC_ + c)*WSZ_;
    if (tid < WSZ_) { s_qi[tid] = qi[tid]; s_ki[tid] = ki[tid]; }
    __syncthreads();
    for (int i = tid; i < 65 * D_; i += 256) {
        int r = i >> 6, d = i & 63;
        float kv, vv;
        if (r == 0) {
            kv = mem_k[((size_t)h*NC_ + c)*D_ + d];
            vv = mem_v[((size_t)h*NC_ + c)*D_ + d];
        } else {
            int tok = s_ki[r-1];
            kv = kg[((size_t)bh*T_ + tok)*D_ + d];
            vv = vg[((size_t)bh*T_ + tok)*D_ + d];
        }
        s_k[i] = kv; s_v[i] = vv;
    }
    __syncthreads();
    const int rowi = tid >> 2, quad = tid & 3;
    const int tok = s_qi[rowi];
    const float* qr = qg + ((size_t)bh*T_ + tok)*D_ + quad*16;
    float qreg[16];
    #pragma unroll
    for (int i = 0; i < 16; i++) qreg[i] = qr[i];
    float m = -1e30f, l = 0.f, acc[16];
    #pragma unroll
    for (int i = 0; i < 16; i++) acc[i] = 0.f;
    for (int j = 0; j < 65; j++) {
        const float* krow = s_k + j*D_ + quad*16;
        float p = 0.f;
        #pragma unroll
        for (int i = 0; i < 16; i++) p += qreg[i] * krow[i];
        p += __shfl_xor(p, 1);
        p += __shfl_xor(p, 2);
        float s = p * 0.125f;
        float nm = fmaxf(m, s);
        float eo = __expf(m - nm);
        float en = __expf(s - nm);
        l = l * eo + en;
        const float* vrow = s_v + j*D_ + quad*16;
        #pragma unroll
        for (int i = 0; i < 16; i++) acc[i] = acc[i]*eo + en*vrow[i];
        m = nm;
    }
    float rl = 1.f / l;
    float* orow = bo + (((size_t)bh*NC_ + c)*WSZ_ + rowi)*D_ + quad*16;
    #pragma unroll
    for (int i4 = 0; i4 < 4; i4++) {
        float4 st = { acc[i4*4+0]*rl, acc[i4*4+1]*rl, acc[i4*4+2]*rl, acc[i4*4+3]*rl };
        *(float4*)(orow + i4*4) = st;
    }
}

// ---------------- Kernel E: gather + divide + aux ----------------
__global__ __launch_bounds__(256) void gather_kernel(
    const float* __restrict__ bo, const u16* __restrict__ entries,
    const int* __restrict__ offsets, const int* __restrict__ counts,
    const double* __restrict__ aux_sum, float* __restrict__ out)
{
    const int tid = threadIdx.x;
    const int g = blockIdx.x * 4 + (tid >> 6);      // bh*T + tok
    const int lane = tid & 63;
    const int bh = g >> 13;
    const int start = offsets[g];
    const int len = counts[g];
    float sum = 0.f;
    for (int e = 0; e < len; e++) {
        int ent = entries[start + e];
        sum += bo[(((size_t)bh << 13) | (unsigned)ent) * D_ + lane];
    }
    out[(size_t)g * D_ + lane] = sum / ((float)len + 1e-5f);
    if (blockIdx.x == 0 && tid == 0)
        out[(size_t)BH * T_ * D_] = (float)(aux_sum[0] * (0.0001 / 33554432.0));
}

extern "C" void kernel_launch(void* const* d_in, const int* in_sizes, int n_in,
                              void* d_out, int out_size, void* d_ws, size_t ws_size,
                              hipStream_t stream)
{
    const float* q      = (const float*)d_in[0];
    const float* k      = (const float*)d_in[1];
    const float* v      = (const float*)d_in[2];
    const float* means  = (const float*)d_in[3];
    const float* mem_k  = (const float*)d_in[4];
    const float* mem_v  = (const float*)d_in[5];
    float* out = (float*)d_out;

    char* ws = (char*)d_ws;
    const size_t SZ_TOK = (size_t)BH * T_ * sizeof(int);          // 1 MiB
    const size_t SZ_IDX = (size_t)BH * NC_ * WSZ_ * sizeof(int);  // 1 MiB
    size_t off = 256;                                             // [0,256): aux double
    const size_t o_counts  = off; off += SZ_TOK;
    const size_t o_offsets = off; off += SZ_TOK;
    const size_t o_cursor  = off; off += SZ_TOK;
    const size_t o_entries = off; off += (size_t)BH * NC_ * WSZ_ * sizeof(u16);
    const size_t o_idxq    = off; off += SZ_IDX;
    const size_t o_idxk    = off; off += SZ_IDX;
    size_t o_bo = (off + 255) & ~(size_t)255;
    off = o_bo + (size_t)BH * NC_ * WSZ_ * D_ * sizeof(float);    // 64 MiB
    size_t o_dbuf = (off + 255) & ~(size_t)255;

    double* aux   = (double*)ws;
    int* counts   = (int*)(ws + o_counts);
    int* offsets  = (int*)(ws + o_offsets);
    int* cursor   = (int*)(ws + o_cursor);
    u16* entries  = (u16*)(ws + o_entries);
    int* idxq     = (int*)(ws + o_idxq);
    int* idxk     = (int*)(ws + o_idxk);
    float* bo     = (float*)(ws + o_bo);
    u16* dbuf     = (u16*)(ws + o_dbuf);

    const size_t per_pair = (size_t)2 * NC_ * T_ * sizeof(u16);   // 4 MiB
    int CH = 32;
    while (CH > 1 && o_dbuf + (size_t)CH * per_pair > ws_size) CH >>= 1;

    hipMemsetAsync(ws, 0, o_offsets, stream);   // zero aux + counts

    for (int p0 = 0; p0 < BH; p0 += CH) {
        dim3 gA(256, CH);
        dist_kernel<<<gA, 256, 0, stream>>>(q, k, means, dbuf, aux, p0);
        dim3 gB(NC_, 2, CH);
        topk_kernel<<<gB, 256, 0, stream>>>(dbuf, q, k, means, idxq, idxk, p0);
    }
    count_kernel<<<dim3(BH * NC_ * WSZ_ / 256), 256, 0, stream>>>(idxq, counts);
    scan_kernel<<<dim3(BH), 256, 0, stream>>>(counts, offsets, cursor);
    fill_kernel<<<dim3(BH * NC_ * WSZ_ / 256), 256, 0, stream>>>(idxq, cursor, entries);
    attn_kernel<<<dim3(NC_, BH), 256, 0, stream>>>(q, k, v, mem_k, mem_v, idxq, idxk, bo);
    gather_kernel<<<dim3(BH * T_ / 4), 256, 0, stream>>>(bo, entries, offsets, counts, aux, out);
}

// Round 6
// 574.795 us; speedup vs baseline: 2.9677x; 1.1306x over previous
//
#include <hip/hip_runtime.h>
#include <math.h>
#include <stdint.h>

#define B_   4
#define H_   8
#define BH   32
#define T_   8192
#define D_   64
#define NC_  128
#define WSZ_ 64
#define CAND_CAP 512

typedef unsigned short u16;
typedef _Float16 frag8h __attribute__((ext_vector_type(8)));
typedef float floatx4 __attribute__((ext_vector_type(4)));

__device__ inline unsigned pack2h(float a, float b) {
    union { _Float16 h[2]; unsigned u; } p;
    p.h[0] = (_Float16)a; p.h[1] = (_Float16)b;
    return p.u;
}

// ---------------- Kernel A v3: fp16 dists + fp64 rnorm precompute ----------------
// LDS: s_mb 18.0 KiB + s_ov 17.0 KiB + misc = ~35.3 KiB -> 4 blocks/CU
__global__ __launch_bounds__(256, 4) void dist_kernel(
    const float* __restrict__ qg, const float* __restrict__ kg,
    const float* __restrict__ means, u16* __restrict__ dbuf,
    double* __restrict__ rnorm, double* __restrict__ aux_sum, int pair0)
{
    __shared__ u16 s_mb[128 * 72];       // fp16 means, stride 72
    __shared__ u16 s_ov[128 * 68];       // overlay: xb (64 x stride 72) then C-stage (128 x stride 68)
    __shared__ int s_argc[64];
    __shared__ float s_aux;
    const int tid = threadIdx.x;
    const int bh = pair0 + blockIdx.y;
    const int h  = bh & 7;
    const int tok0 = blockIdx.x * 64;            // within [0, 2T)
    const int isK  = (tok0 >= T_) ? 1 : 0;
    const int tloc0 = isK ? tok0 - T_ : tok0;
    const float* src = isK ? kg : qg;

    if (tid == 0) s_aux = 0.f;
    // means -> LDS fp16
    {
        const float* mh = means + (size_t)h * NC_ * D_;
        #pragma unroll
        for (int it = 0; it < 8; it++) {
            int i = it * 1024 + tid * 4;
            float4 mv = *(const float4*)(mh + i);
            uint2 pk = { pack2h(mv.x, mv.y), pack2h(mv.z, mv.w) };
            *(uint2*)&s_mb[(i >> 6) * 72 + (i & 63)] = pk;
        }
    }
    // token row -> registers; fp64 norm; fp32 normalize; fp16 slice -> xb
    const int row = tid >> 2, sub = tid & 3;
    float xr[16];
    {
        const float* sp = src + ((size_t)bh * T_ + tloc0 + row) * D_ + sub * 16;
        #pragma unroll
        for (int e4 = 0; e4 < 4; e4++) {
            float4 xv = *(const float4*)(sp + e4 * 4);
            xr[e4*4+0] = xv.x; xr[e4*4+1] = xv.y; xr[e4*4+2] = xv.z; xr[e4*4+3] = xv.w;
        }
        double dss = 0.0;
        #pragma unroll
        for (int e = 0; e < 16; e++) { double dv = (double)xr[e]; dss += dv * dv; }
        dss += __shfl_xor(dss, 1); dss += __shfl_xor(dss, 2);
        if (sub == 0) {
            double rn64 = 1.0 / fmax(sqrt(dss), 1e-12);
            rnorm[((size_t)bh * 2 + isK) * T_ + tloc0 + row] = rn64;
        }
        float ss = (float)dss;
        const float rn = 1.0f / fmaxf(sqrtf(ss), 1e-12f);
        #pragma unroll
        for (int e = 0; e < 16; e++) xr[e] *= rn;
        uint4 p0 = { pack2h(xr[0],xr[1]), pack2h(xr[2],xr[3]), pack2h(xr[4],xr[5]), pack2h(xr[6],xr[7]) };
        uint4 p1 = { pack2h(xr[8],xr[9]), pack2h(xr[10],xr[11]), pack2h(xr[12],xr[13]), pack2h(xr[14],xr[15]) };
        *(uint4*)&s_ov[row * 72 + sub * 16]     = p0;
        *(uint4*)&s_ov[row * 72 + sub * 16 + 8] = p1;
    }
    __syncthreads();                               // mb + xb visible
    const int w = tid >> 6, lane = tid & 63;
    const int mrow = lane & 15, quad = lane >> 4;
    const frag8h a0 = *(const frag8h*)&s_ov[(w*16 + mrow)*72 + quad*8];
    const frag8h a1 = *(const frag8h*)&s_ov[(w*16 + mrow)*72 + 32 + quad*8];
    __syncthreads();                               // a-frag reads done before stage overwrite
    {
        float bv[4]; int bc[4];
        #pragma unroll
        for (int r = 0; r < 4; r++) { bv[r] = -1e30f; bc[r] = 0; }
        const int tokw = w * 16 + quad * 4;        // block-local token base of my C rows
        #pragma unroll
        for (int n = 0; n < 8; n++) {
            const frag8h b0 = *(const frag8h*)&s_mb[(n*16 + mrow)*72 + quad*8];
            const frag8h b1 = *(const frag8h*)&s_mb[(n*16 + mrow)*72 + 32 + quad*8];
            floatx4 acc = {0.f, 0.f, 0.f, 0.f};
            acc = __builtin_amdgcn_mfma_f32_16x16x32_f16(a0, b0, acc, 0, 0, 0);
            acc = __builtin_amdgcn_mfma_f32_16x16x32_f16(a1, b1, acc, 0, 0, 0);
            const int cc = n*16 + mrow;            // cluster (C col = lane&15)
            uint2 pk = { pack2h(acc[0], acc[1]), pack2h(acc[2], acc[3]) };
            *(uint2*)&s_ov[cc * 68 + tokw] = pk;   // stage
            #pragma unroll
            for (int r = 0; r < 4; r++)
                if (acc[r] > bv[r]) { bv[r] = acc[r]; bc[r] = cc; }   // n asc => lowest c on ties
        }
        #pragma unroll
        for (int m = 1; m < 16; m <<= 1) {
            #pragma unroll
            for (int r = 0; r < 4; r++) {
                float ov = __shfl_xor(bv[r], m);
                int   oc = __shfl_xor(bc[r], m);
                if (ov > bv[r] || (ov == bv[r] && oc < bc[r])) { bv[r] = ov; bc[r] = oc; }
            }
        }
        if (mrow == 0) {
            #pragma unroll
            for (int r = 0; r < 4; r++) s_argc[tokw + r] = bc[r];
        }
    }
    __syncthreads();                               // stage + argc visible
    // coalesced dbuf writeout: 16 lanes cover one 128 B cluster-row segment
    {
        const size_t dbase = ((size_t)blockIdx.y*2 + isK) * NC_;
        #pragma unroll
        for (int it = 0; it < 8; it++) {
            int idx = it * 256 + tid;              // 0..2047
            int crow = idx >> 4;                   // cluster 0..127
            int colg = (idx & 15) * 4;             // token 0..60 step 4
            uint2 pk = *(const uint2*)&s_ov[crow * 68 + colg];
            *(uint2*)&dbuf[(dbase + crow) * T_ + tloc0 + colg] = pk;
        }
    }
    // aux residual from registers
    {
        const int c = s_argc[row];
        const float* mr = means + ((size_t)h*NC_ + c)*D_ + sub*16;
        float rs = 0.f;
        #pragma unroll
        for (int e4 = 0; e4 < 4; e4++) {
            float4 mv = *(const float4*)(mr + e4*4);
            float d0 = xr[e4*4+0]-mv.x, d1 = xr[e4*4+1]-mv.y;
            float d2 = xr[e4*4+2]-mv.z, d3 = xr[e4*4+3]-mv.w;
            rs += d0*d0 + d1*d1 + d2*d2 + d3*d3;
        }
        rs += __shfl_xor(rs, 1); rs += __shfl_xor(rs, 2);
        if (sub == 0) atomicAdd(&s_aux, rs);
    }
    __syncthreads();
    if (tid == 0) atomicAdd(aux_sum, (double)s_aux);
}

// ---------------- Kernel B v4: fp16 keys, 2-bin margin, rnorm-assisted fp64 rank ----------------
__global__ __launch_bounds__(256) void topk_kernel(
    const u16* __restrict__ dbuf, const float* __restrict__ qg,
    const float* __restrict__ kg, const float* __restrict__ means,
    const double* __restrict__ rnorm,
    int* __restrict__ idx_q, int* __restrict__ idx_k, int pair0)
{
    __shared__ int s_hist[2048];          // 4096 logical bins, 2x16-bit packed
    __shared__ int s_scan[256];
    __shared__ int s_wtot[4];
    __shared__ int s_B, s_cnt;
    __shared__ int s_cand[CAND_CAP];
    __shared__ unsigned long long s_key[CAND_CAP];
    __shared__ int s_tok[CAND_CAP];
    __shared__ double s_mean[64];

    const int tid = threadIdx.x;
    const int lane = tid & 63, w = tid >> 6;
    const int c = blockIdx.x, isK = blockIdx.y, pl = blockIdx.z;
    const int bh = pair0 + pl, h = bh & 7;
    const u16* row = dbuf + (((size_t)pl*2 + isK)*NC_ + c)*T_;

    for (int i = tid; i < 2048; i += 256) s_hist[i] = 0;
    if (tid < 64) s_mean[tid] = (double)means[((size_t)h*NC_ + c)*D_ + tid];
    __syncthreads();
    u16 keys[32];
    {
        const uint4* rv = (const uint4*)(row + tid * 32);
        #pragma unroll
        for (int j4 = 0; j4 < 4; j4++) {
            uint4 pk = rv[j4];
            unsigned int wd[4] = {pk.x, pk.y, pk.z, pk.w};
            #pragma unroll
            for (int w2 = 0; w2 < 4; w2++) {
                u16 lo = (u16)(wd[w2] & 0xffffu), hi = (u16)(wd[w2] >> 16);
                keys[j4*8 + w2*2 + 0] = (lo & 0x8000u) ? (u16)(~lo) : (u16)(lo | 0x8000u);
                keys[j4*8 + w2*2 + 1] = (hi & 0x8000u) ? (u16)(~hi) : (u16)(hi | 0x8000u);
            }
        }
    }
    #pragma unroll
    for (int j = 0; j < 32; j++) {
        int b = keys[j] >> 4;
        atomicAdd(&s_hist[b >> 1], 1 << ((b & 1) * 16));
    }
    __syncthreads();
    int cs = 0;
    #pragma unroll
    for (int k2 = 0; k2 < 8; k2++) { int v2 = s_hist[tid*8 + k2]; cs += (v2 & 0xffff) + (v2 >> 16); }
    int sv = cs;
    #pragma unroll
    for (int off = 1; off < 64; off <<= 1) {
        int o = __shfl_down(sv, off);
        if (lane + off < 64) sv += o;
    }
    if (lane == 0) s_wtot[w] = sv;
    __syncthreads();
    {
        int add = 0;
        #pragma unroll
        for (int w2 = 0; w2 < 4; w2++) if (w2 > w) add += s_wtot[w2];
        s_scan[tid] = sv + add;
    }
    __syncthreads();
    {
        int Tj = s_scan[tid];
        int Tn = (tid < 255) ? s_scan[tid + 1] : 0;
        if (Tj >= WSZ_ && Tn < WSZ_) {
            int running = Tn, Bb = tid * 16;
            for (int b2 = tid*16 + 15; b2 >= tid*16; b2--) {
                running += (s_hist[b2 >> 1] >> ((b2 & 1) * 16)) & 0xffff;
                if (running >= WSZ_) { Bb = b2; break; }
            }
            s_B = Bb;
        }
    }
    __syncthreads();
    // fp16 bin = 16 ulp (~0.031 at cutoff); 2-bin margin ~0.062 >> ~1e-3 fp16/MFMA error
    int thr = s_B - 2; if (thr < 0) thr = 0;
    for (;;) {
        if (tid == 0) s_cnt = 0;
        __syncthreads();
        #pragma unroll
        for (int j = 0; j < 32; j++) {
            if ((int)(keys[j] >> 4) >= thr) {
                int p = atomicAdd(&s_cnt, 1);
                if (p < CAND_CAP) s_cand[p] = tid*32 + j;
            }
        }
        __syncthreads();
        if (s_cnt <= CAND_CAP) break;
        thr++;
        __syncthreads();
    }
    const int M = s_cnt;                        // >= 64 by construction
    const float* src = isK ? kg : qg;
    const double* rnrow = rnorm + ((size_t)bh * 2 + isK) * T_;
    {
        const int sub = tid & 3;
        for (int ci = (tid >> 2); ci < M; ci += 64) {
            const int tok = s_cand[ci];
            const float* xr = src + ((size_t)bh*T_ + tok)*D_ + sub*16;
            double dot = 0.0;
            #pragma unroll
            for (int e4 = 0; e4 < 4; e4++) {
                float4 xv4 = *(const float4*)(xr + e4*4);
                const double* mm = &s_mean[sub*16 + e4*4];
                dot += (double)xv4.x*mm[0] + (double)xv4.y*mm[1]
                     + (double)xv4.z*mm[2] + (double)xv4.w*mm[3];
            }
            dot += __shfl_xor(dot, 1); dot += __shfl_xor(dot, 2);
            if (sub == 0) {
                double val = dot * rnrow[tok];
                unsigned long long u = (unsigned long long)__double_as_longlong(val);
                u = (u & 0x8000000000000000ull) ? ~u : (u | 0x8000000000000000ull);
                s_key[ci] = u;
                s_tok[ci] = tok;
            }
        }
    }
    __syncthreads();
    int* dst = (isK ? idx_k : idx_q) + ((size_t)bh*NC_ + c)*WSZ_;
    for (int p = tid; p < M; p += 256) {
        unsigned long long kp = s_key[p];
        int ip = s_tok[p];
        int rank = 0;
        for (int j = 0; j < M; j++) {
            unsigned long long kj = s_key[j];
            int ij = s_tok[j];
            if (kj > kp || (kj == kp && ij < ip)) rank++;
        }
        if (rank < WSZ_) dst[rank] = ip;
    }
}

// ---------------- Kernel C1: selection counts ----------------
__global__ __launch_bounds__(256) void count_kernel(
    const int* __restrict__ idx_q, int* __restrict__ counts)
{
    int i = blockIdx.x * 256 + threadIdx.x;   // 0 .. BH*NC*WSZ-1
    int bh = i >> 13;
    atomicAdd(&counts[bh * T_ + idx_q[i]], 1);
}

// ---------------- Kernel C2: per-bh exclusive scan of counts -> offsets, cursor ----------------
__global__ __launch_bounds__(256) void scan_kernel(
    const int* __restrict__ counts, int* __restrict__ offsets, int* __restrict__ cursor)
{
    __shared__ int s_tmp[256];
    const int tid = threadIdx.x, bh = blockIdx.x;
    const int base = bh * T_;
    int c[32], s = 0;
    #pragma unroll
    for (int j = 0; j < 32; j++) { c[j] = counts[base + tid*32 + j]; s += c[j]; }
    s_tmp[tid] = s;
    __syncthreads();
    for (int off = 1; off < 256; off <<= 1) {
        int add = (tid >= off) ? s_tmp[tid - off] : 0;
        __syncthreads();
        s_tmp[tid] += add;
        __syncthreads();
    }
    int running = s_tmp[tid] - s + bh * (NC_ * WSZ_);   // exclusive prefix + bh base
    #pragma unroll
    for (int j = 0; j < 32; j++) {
        offsets[base + tid*32 + j] = running;
        cursor [base + tid*32 + j] = running;
        running += c[j];
    }
}

// ---------------- Kernel C3: fill CSR entries ----------------
__global__ __launch_bounds__(256) void fill_kernel(
    const int* __restrict__ idx_q, int* __restrict__ cursor, u16* __restrict__ entries)
{
    int i = blockIdx.x * 256 + threadIdx.x;   // 0 .. BH*NC*WSZ-1
    int bh = i >> 13;
    int tok = idx_q[i];
    int pos = atomicAdd(&cursor[bh * T_ + tok], 1);
    entries[pos] = (u16)(i & 8191);           // c*WSZ + slot
}

// ---------------- Kernel D: per-cluster attention -> dense bo (no atomics) ----------------
__global__ __launch_bounds__(256) void attn_kernel(
    const float* __restrict__ qg, const float* __restrict__ kg, const float* __restrict__ vg,
    const float* __restrict__ mem_k, const float* __restrict__ mem_v,
    const int* __restrict__ idx_q, const int* __restrict__ idx_k,
    float* __restrict__ bo)
{
    __shared__ float s_k[65 * D_];
    __shared__ float s_v[65 * D_];
    __shared__ int s_qi[WSZ_], s_ki[WSZ_];
    const int tid = threadIdx.x;
    const int c = blockIdx.x, bh = blockIdx.y, h = bh & 7;
    const int* qi = idx_q + ((size_t)bh*NC_ + c)*WSZ_;
    const int* ki = idx_k + ((size_t)bh*NC_ + c)*WSZ_;
    if (tid < WSZ_) { s_qi[tid] = qi[tid]; s_ki[tid] = ki[tid]; }
    __syncthreads();
    for (int i = tid; i < 65 * D_; i += 256) {
        int r = i >> 6, d = i & 63;
        float kv, vv;
        if (r == 0) {
            kv = mem_k[((size_t)h*NC_ + c)*D_ + d];
            vv = mem_v[((size_t)h*NC_ + c)*D_ + d];
        } else {
            int tok = s_ki[r-1];
            kv = kg[((size_t)bh*T_ + tok)*D_ + d];
            vv = vg[((size_t)bh*T_ + tok)*D_ + d];
        }
        s_k[i] = kv; s_v[i] = vv;
    }
    __syncthreads();
    const int rowi = tid >> 2, quad = tid & 3;
    const int tok = s_qi[rowi];
    const float* qr = qg + ((size_t)bh*T_ + tok)*D_ + quad*16;
    float qreg[16];
    #pragma unroll
    for (int i = 0; i < 16; i++) qreg[i] = qr[i];
    float m = -1e30f, l = 0.f, acc[16];
    #pragma unroll
    for (int i = 0; i < 16; i++) acc[i] = 0.f;
    for (int j = 0; j < 65; j++) {
        const float* krow = s_k + j*D_ + quad*16;
        float p = 0.f;
        #pragma unroll
        for (int i = 0; i < 16; i++) p += qreg[i] * krow[i];
        p += __shfl_xor(p, 1);
        p += __shfl_xor(p, 2);
        float s = p * 0.125f;
        float nm = fmaxf(m, s);
        float eo = __expf(m - nm);
        float en = __expf(s - nm);
        l = l * eo + en;
        const float* vrow = s_v + j*D_ + quad*16;
        #pragma unroll
        for (int i = 0; i < 16; i++) acc[i] = acc[i]*eo + en*vrow[i];
        m = nm;
    }
    float rl = 1.f / l;
    float* orow = bo + (((size_t)bh*NC_ + c)*WSZ_ + rowi)*D_ + quad*16;
    #pragma unroll
    for (int i4 = 0; i4 < 4; i4++) {
        float4 st = { acc[i4*4+0]*rl, acc[i4*4+1]*rl, acc[i4*4+2]*rl, acc[i4*4+3]*rl };
        *(float4*)(orow + i4*4) = st;
    }
}

// ---------------- Kernel E: gather + divide + aux ----------------
__global__ __launch_bounds__(256) void gather_kernel(
    const float* __restrict__ bo, const u16* __restrict__ entries,
    const int* __restrict__ offsets, const int* __restrict__ counts,
    const double* __restrict__ aux_sum, float* __restrict__ out)
{
    const int tid = threadIdx.x;
    const int g = blockIdx.x * 4 + (tid >> 6);      // bh*T + tok
    const int lane = tid & 63;
    const int bh = g >> 13;
    const int start = offsets[g];
    const int len = counts[g];
    float sum = 0.f;
    for (int e = 0; e < len; e++) {
        int ent = entries[start + e];
        sum += bo[(((size_t)bh << 13) | (unsigned)ent) * D_ + lane];
    }
    out[(size_t)g * D_ + lane] = sum / ((float)len + 1e-5f);
    if (blockIdx.x == 0 && tid == 0)
        out[(size_t)BH * T_ * D_] = (float)(aux_sum[0] * (0.0001 / 33554432.0));
}

extern "C" void kernel_launch(void* const* d_in, const int* in_sizes, int n_in,
                              void* d_out, int out_size, void* d_ws, size_t ws_size,
                              hipStream_t stream)
{
    const float* q      = (const float*)d_in[0];
    const float* k      = (const float*)d_in[1];
    const float* v      = (const float*)d_in[2];
    const float* means  = (const float*)d_in[3];
    const float* mem_k  = (const float*)d_in[4];
    const float* mem_v  = (const float*)d_in[5];
    float* out = (float*)d_out;

    char* ws = (char*)d_ws;
    const size_t SZ_TOK = (size_t)BH * T_ * sizeof(int);          // 1 MiB
    const size_t SZ_IDX = (size_t)BH * NC_ * WSZ_ * sizeof(int);  // 1 MiB
    size_t off = 256;                                             // [0,256): aux double
    const size_t o_counts  = off; off += SZ_TOK;
    const size_t o_offsets = off; off += SZ_TOK;
    const size_t o_cursor  = off; off += SZ_TOK;
    const size_t o_entries = off; off += (size_t)BH * NC_ * WSZ_ * sizeof(u16);
    const size_t o_idxq    = off; off += SZ_IDX;
    const size_t o_idxk    = off; off += SZ_IDX;
    const size_t o_rnorm   = off; off += (size_t)BH * 2 * T_ * sizeof(double);  // 4 MiB
    size_t o_bo = (off + 255) & ~(size_t)255;
    off = o_bo + (size_t)BH * NC_ * WSZ_ * D_ * sizeof(float);    // 64 MiB
    size_t o_dbuf = (off + 255) & ~(size_t)255;

    double* aux   = (double*)ws;
    int* counts   = (int*)(ws + o_counts);
    int* offsets  = (int*)(ws + o_offsets);
    int* cursor   = (int*)(ws + o_cursor);
    u16* entries  = (u16*)(ws + o_entries);
    int* idxq     = (int*)(ws + o_idxq);
    int* idxk     = (int*)(ws + o_idxk);
    double* rnorm = (double*)(ws + o_rnorm);
    float* bo     = (float*)(ws + o_bo);
    u16* dbuf     = (u16*)(ws + o_dbuf);

    const size_t per_pair = (size_t)2 * NC_ * T_ * sizeof(u16);   // 4 MiB
    int CH = 32;
    while (CH > 1 && o_dbuf + (size_t)CH * per_pair > ws_size) CH >>= 1;

    hipMemsetAsync(ws, 0, o_offsets, stream);   // zero aux + counts

    for (int p0 = 0; p0 < BH; p0 += CH) {
        dim3 gA(256, CH);
        dist_kernel<<<gA, 256, 0, stream>>>(q, k, means, dbuf, rnorm, aux, p0);
        dim3 gB(NC_, 2, CH);
        topk_kernel<<<gB, 256, 0, stream>>>(dbuf, q, k, means, rnorm, idxq, idxk, p0);
    }
    count_kernel<<<dim3(BH * NC_ * WSZ_ / 256), 256, 0, stream>>>(idxq, counts);
    scan_kernel<<<dim3(BH), 256, 0, stream>>>(counts, offsets, cursor);
    fill_kernel<<<dim3(BH * NC_ * WSZ_ / 256), 256, 0, stream>>>(idxq, cursor, entries);
    attn_kernel<<<dim3(NC_, BH), 256, 0, stream>>>(q, k, v, mem_k, mem_v, idxq, idxk, bo);
    gather_kernel<<<dim3(BH * T_ / 4), 256, 0, stream>>>(bo, entries, offsets, counts, aux, out);
}